// Round 7
// baseline (687.457 us; speedup 1.0000x reference)
//
#include <hip/hip_runtime.h>
#include <hip/hip_fp16.h>
#include <math.h>

// Problem constants (match reference)
#define NN   100000
#define EE   3200000
#define GG   512
#define INC  128
#define D1   64        // H1*C1 = 8*8
#define OUTC 64
#define HID  128
#define NEG  0.2f

// Direct CSR: 128-node bins define col segment bases (bin*BCAP)
#define BINS   782     // ceil(NN/128)
#define BNODE  128
#define BSHIFT 7
#define BMASK  127
#define BCAP   4800    // Binomial mean 4096 + 11 sigma; overflow-guarded
#define BKBLK 1563     // ceil(EE/2048) edge blocks
#define NGB 391        // ceil(NN/256) register-tiled GEMM blocks

typedef __attribute__((ext_vector_type(2))) float v2f;

// Node record layout (both layers, shared buffer REC, 128B/node aligned):
//   bytes  0..63 : 64 x fp8 h-row
//   bytes 64..79 : layer1: 8 x half a_src   | layer2: float a_src at byte 64
//   bytes 80..127: pad
// One 128B line per edge-gather: the a_src read lands in the SAME line as
// the h gather -> second L1 request per edge becomes a line hit.

// ===========================================================================
// FUSED: [blocks 0..NGB) = lin1 GEMM (long blocks, launched first)
//        [NGB..) = per-node degree count (direct-CSR pass A; reads dstv only,
//        3.2M no-return atomics to 400KB L2-resident counters, no writes).
// Replaces the bucket scatter: no 15MB intermediate, no write-allocate
// amplification (R5: 51MB WRITE_SIZE for 12.8MB of bucket data).
// ===========================================================================
__global__ __launch_bounds__(256, 3)
void k_fused(const int* __restrict__ dstv, int* __restrict__ cnt_node,
             const float* __restrict__ x, const float* __restrict__ W1,
             const float* __restrict__ att_s, const float* __restrict__ att_d,
             unsigned int* __restrict__ rec, float* __restrict__ a_d) {
    __shared__ __align__(16) char smem[49152];
    int tid = threadIdx.x;
    if (blockIdx.x < NGB) {
        // ---------------- lin1: rec = x @ W1 (fp8 + a_s), attention dots ---
        float4* sW4 = (float4*)smem;                        // 32768 B
        float (*sxT)[256] = (float(*)[256])(smem + 32768);  // 16x256x4 = 16384 B
        const float4* W4 = (const float4*)W1;
        for (int i = tid; i < 128 * 16; i += 256) sW4[i] = W4[i];
        int node0 = blockIdx.x * 256;
        int rg = tid >> 3, cg = tid & 7;     // 32 row-groups x 8 col-groups
        float acc[8][8];
#pragma unroll
        for (int ii = 0; ii < 8; ++ii)
#pragma unroll
            for (int jj = 0; jj < 8; ++jj) acc[ii][jj] = 0.f;
        const float4* x4 = (const float4*)x;
        for (int kt = 0; kt < 8; ++kt) {     // K tiles of 16
            if (kt) __syncthreads();         // readers done with prev tile
#pragma unroll
            for (int q = 0; q < 4; ++q) {    // stage 256 rows x 16 k, transposed
                int i = q * 256 + tid;
                int r = i >> 2, kc = i & 3;
                int gn = node0 + r;
                float4 v = {0.f, 0.f, 0.f, 0.f};
                if (gn < NN) v = x4[(size_t)gn * 32 + kt * 4 + kc];
                int cs = r ^ (kc << 3);      // swizzle: s = (k>>2)<<3, k>>2 = kc
                sxT[kc * 4 + 0][cs] = v.x;
                sxT[kc * 4 + 1][cs] = v.y;
                sxT[kc * 4 + 2][cs] = v.z;
                sxT[kc * 4 + 3][cs] = v.w;
            }
            __syncthreads();
#pragma unroll 4
            for (int kk = 0; kk < 16; ++kk) {
                int sw = (kk >> 2) << 3;
                const float* xr = &sxT[kk][(rg * 8) ^ sw];
                float4 xa = *(const float4*)xr;
                float4 xb = *(const float4*)(xr + 4);
                int kg = kt * 16 + kk;
                float4 wa = sW4[kg * 16 + cg * 2];
                float4 wb = sW4[kg * 16 + cg * 2 + 1];
                float xv[8] = {xa.x, xa.y, xa.z, xa.w, xb.x, xb.y, xb.z, xb.w};
                float wv[8] = {wa.x, wa.y, wa.z, wa.w, wb.x, wb.y, wb.z, wb.w};
#pragma unroll
                for (int ii = 0; ii < 8; ++ii)
#pragma unroll
                    for (int jj = 0; jj < 8; ++jj)
                        acc[ii][jj] = fmaf(xv[ii], wv[jj], acc[ii][jj]);
            }
        }
        // epilogue: fp8 pack + per-head attention dots (head == cg, no reduce)
        float4 s0 = ((const float4*)att_s)[cg * 2];
        float4 s1 = ((const float4*)att_s)[cg * 2 + 1];
        float4 d0 = ((const float4*)att_d)[cg * 2];
        float4 d1 = ((const float4*)att_d)[cg * 2 + 1];
        uint2* hp2 = (uint2*)rec;
        __half* ash = (__half*)rec;
#pragma unroll
        for (int ii = 0; ii < 8; ++ii) {
            int n = node0 + rg * 8 + ii;
            if (n < NN) {
                float* a = acc[ii];
                int p0 = __builtin_amdgcn_cvt_pk_fp8_f32(a[0], a[1], 0, false);
                p0 = __builtin_amdgcn_cvt_pk_fp8_f32(a[2], a[3], p0, true);
                int p1 = __builtin_amdgcn_cvt_pk_fp8_f32(a[4], a[5], 0, false);
                p1 = __builtin_amdgcn_cvt_pk_fp8_f32(a[6], a[7], p1, true);
                uint2 pk; pk.x = (unsigned)p0; pk.y = (unsigned)p1;
                hp2[n * 16 + cg] = pk;       // record stride 128B = 16 uint2
                float as = a[0] * s0.x;
                as = fmaf(a[1], s0.y, as); as = fmaf(a[2], s0.z, as);
                as = fmaf(a[3], s0.w, as); as = fmaf(a[4], s1.x, as);
                as = fmaf(a[5], s1.y, as); as = fmaf(a[6], s1.z, as);
                as = fmaf(a[7], s1.w, as);
                float ad = a[0] * d0.x;
                ad = fmaf(a[1], d0.y, ad); ad = fmaf(a[2], d0.z, ad);
                ad = fmaf(a[3], d0.w, ad); ad = fmaf(a[4], d1.x, ad);
                ad = fmaf(a[5], d1.y, ad); ad = fmaf(a[6], d1.z, ad);
                ad = fmaf(a[7], d1.w, ad);
                ash[n * 64 + 32 + cg] = __float2half(as);   // byte 64 + 2*cg
                a_d[n * 8 + cg] = ad;
            }
        }
    } else {
        // ---------------- degree count (pass A) ----------------
        int base = (blockIdx.x - NGB) * 2048;
#pragma unroll
        for (int q = 0; q < 2; ++q) {
            int e = base + (q * 256 + tid) * 4;
            if (e < EE) {                      // EE % 4 == 0 -> int4 safe
                int4 dd = *(const int4*)(dstv + e);
                atomicAdd(&cnt_node[dd.x], 1); // no-return global atomics
                atomicAdd(&cnt_node[dd.y], 1);
                atomicAdd(&cnt_node[dd.z], 1);
                atomicAdd(&cnt_node[dd.w], 1);
            }
        }
    }
}

// ===========================================================================
// Pass B1: per-bin exclusive scan of node degrees -> rbeg/rend/cur.
// 782 blocks x 128 threads; trivial (~3us).
// ===========================================================================
__global__ __launch_bounds__(128)
void k_scan(const int* __restrict__ cnt_node, int* __restrict__ rbeg,
            int* __restrict__ rend, int* __restrict__ cur) {
    __shared__ int tmp[BNODE];
    int b = blockIdx.x, tid = threadIdx.x;
    int n = b * BNODE + tid;                 // < BINS*BNODE, array sized so
    int c = cnt_node[n];                     // zero beyond NN (memset)
    tmp[tid] = c;
    __syncthreads();
    for (int off = 1; off < BNODE; off <<= 1) {
        int t = (tid >= off) ? tmp[tid - off] : 0;
        __syncthreads();
        tmp[tid] += t;
        __syncthreads();
    }
    if (n < NN) {
        int lim = b * BCAP + BCAP;
        int rb = b * BCAP + (tmp[tid] - c);
        if (rb > lim) rb = lim;
        int re = rb + c; if (re > lim) re = lim;
        rbeg[n] = rb; rend[n] = re; cur[n] = rb;
    }
}

// ===========================================================================
// Pass B2: scatter src into col at atomic per-node cursor positions.
// 3.2M return-atomics to 400KB (L2) + 3.2M scattered 4B writes. Replaces
// the old bucket write + binCSR double-read + col rewrite.
// ===========================================================================
__global__ __launch_bounds__(256)
void k_scatter(const int* __restrict__ srcv, const int* __restrict__ dstv,
               int* __restrict__ cur, int* __restrict__ col) {
    int tid = threadIdx.x;
    int base = blockIdx.x * 2048;
#pragma unroll
    for (int q = 0; q < 2; ++q) {
        int e = base + (q * 256 + tid) * 4;
        if (e < EE) {
            int4 ss = *(const int4*)(srcv + e);
            int4 dd = *(const int4*)(dstv + e);
            int p0 = atomicAdd(&cur[dd.x], 1);
            if (p0 < ((dd.x >> BSHIFT) + 1) * BCAP) col[p0] = ss.x;
            int p1 = atomicAdd(&cur[dd.y], 1);
            if (p1 < ((dd.y >> BSHIFT) + 1) * BCAP) col[p1] = ss.y;
            int p2 = atomicAdd(&cur[dd.z], 1);
            if (p2 < ((dd.z >> BSHIFT) + 1) * BCAP) col[p2] = ss.z;
            int p3 = atomicAdd(&cur[dd.w], 1);
            if (p3 < ((dd.w >> BSHIFT) + 1) * BCAP) col[p3] = ss.w;
        }
    }
}

// ===========================================================================
// Agg layer 1 (8 heads). Wave = 2 nodes x (4 edge-slots x 8 lanes), lane&7 =
// head = ch-group (uint2 fp8 row slice). 1-deep index prefetch (pad-safe).
// a_src read from the SAME 128B record line as the h gather.
// ===========================================================================
__global__ __launch_bounds__(256, 8)
void k_gat_agg1(const int* __restrict__ rbeg, const int* __restrict__ rend,
                const int* __restrict__ col,
                const unsigned int* __restrict__ rec, const float* __restrict__ a_d,
                const float* __restrict__ b1, float* __restrict__ out) {
    int wv = threadIdx.x >> 6;
    int lane = threadIdx.x & 63;
    int half = lane >> 5;
    int d = blockIdx.x * 8 + wv * 2 + half;
    int gs = (lane >> 3) & 3;   // slot within node
    int l = lane & 7;           // head / ch-group
    int rb = rbeg[d], re = rend[d];
    float adh = a_d[d * 8 + l];
    const uint2* hp = (const uint2*)rec;
    const __half* asr = (const __half*)rec;
    uint2 rself = hp[d * 16 + l];
    float asself = __half2float(asr[d * 64 + 32 + l]);
    float ac[8] = {0.f,0.f,0.f,0.f,0.f,0.f,0.f,0.f};
    float denom = 0.f;
    int e = rb + gs;
    int s[4];
#pragma unroll
    for (int q = 0; q < 4; ++q) s[q] = col[e + 4 * q];   // pad-safe preload
    for (; e + 12 < re; ) {
        uint2 rr[4]; float asv[4]; int sn[4];
#pragma unroll
        for (int q = 0; q < 4; ++q) rr[q] = hp[(unsigned)(s[q] * 16 + l)];
#pragma unroll
        for (int q = 0; q < 4; ++q) asv[q] = __half2float(asr[(unsigned)(s[q] * 64 + 32 + l)]);
        int en = e + 16;
#pragma unroll
        for (int q = 0; q < 4; ++q) sn[q] = col[en + 4 * q];  // prefetch next
#pragma unroll
        for (int q = 0; q < 4; ++q) {
            float xx = asv[q] + adh;
            xx = xx >= 0.f ? xx : NEG * xx;
            float w = __expf(xx);
            denom += w;
            v2f f0 = __builtin_amdgcn_cvt_pk_f32_fp8((int)rr[q].x, false);
            v2f f1 = __builtin_amdgcn_cvt_pk_f32_fp8((int)rr[q].x, true);
            v2f f2 = __builtin_amdgcn_cvt_pk_f32_fp8((int)rr[q].y, false);
            v2f f3 = __builtin_amdgcn_cvt_pk_f32_fp8((int)rr[q].y, true);
            ac[0] = fmaf(f0.x, w, ac[0]); ac[1] = fmaf(f0.y, w, ac[1]);
            ac[2] = fmaf(f1.x, w, ac[2]); ac[3] = fmaf(f1.y, w, ac[3]);
            ac[4] = fmaf(f2.x, w, ac[4]); ac[5] = fmaf(f2.y, w, ac[5]);
            ac[6] = fmaf(f3.x, w, ac[6]); ac[7] = fmaf(f3.y, w, ac[7]);
        }
        e = en;
#pragma unroll
        for (int q = 0; q < 4; ++q) s[q] = sn[q];
    }
    for (; e < re; e += 4) {
        int s0 = col[e];
        uint2 r0 = hp[(unsigned)(s0 * 16 + l)];
        float x0 = __half2float(asr[(unsigned)(s0 * 64 + 32 + l)]) + adh;
        x0 = x0 >= 0.f ? x0 : NEG * x0;
        float w0 = __expf(x0);
        denom += w0;
        v2f f0 = __builtin_amdgcn_cvt_pk_f32_fp8((int)r0.x, false);
        v2f f1 = __builtin_amdgcn_cvt_pk_f32_fp8((int)r0.x, true);
        v2f f2 = __builtin_amdgcn_cvt_pk_f32_fp8((int)r0.y, false);
        v2f f3 = __builtin_amdgcn_cvt_pk_f32_fp8((int)r0.y, true);
        ac[0] = fmaf(f0.x, w0, ac[0]); ac[1] = fmaf(f0.y, w0, ac[1]);
        ac[2] = fmaf(f1.x, w0, ac[2]); ac[3] = fmaf(f1.y, w0, ac[3]);
        ac[4] = fmaf(f2.x, w0, ac[4]); ac[5] = fmaf(f2.y, w0, ac[5]);
        ac[6] = fmaf(f3.x, w0, ac[6]); ac[7] = fmaf(f3.y, w0, ac[7]);
    }
    if (gs == 0) {      // self-loop contribution
        float es = asself + adh;
        es = es >= 0.f ? es : NEG * es;
        float w = __expf(es);
        denom += w;
        v2f f0 = __builtin_amdgcn_cvt_pk_f32_fp8((int)rself.x, false);
        v2f f1 = __builtin_amdgcn_cvt_pk_f32_fp8((int)rself.x, true);
        v2f f2 = __builtin_amdgcn_cvt_pk_f32_fp8((int)rself.y, false);
        v2f f3 = __builtin_amdgcn_cvt_pk_f32_fp8((int)rself.y, true);
        ac[0] = fmaf(f0.x, w, ac[0]); ac[1] = fmaf(f0.y, w, ac[1]);
        ac[2] = fmaf(f1.x, w, ac[2]); ac[3] = fmaf(f1.y, w, ac[3]);
        ac[4] = fmaf(f2.x, w, ac[4]); ac[5] = fmaf(f2.y, w, ac[5]);
        ac[6] = fmaf(f3.x, w, ac[6]); ac[7] = fmaf(f3.y, w, ac[7]);
    }
#pragma unroll
    for (int i = 0; i < 8; ++i) {     // reduce 4 slots (stays within 32-half)
        ac[i] += __shfl_xor(ac[i], 8, 64);
        ac[i] += __shfl_xor(ac[i], 16, 64);
    }
    denom += __shfl_xor(denom, 8, 64);
    denom += __shfl_xor(denom, 16, 64);
    if (gs == 0) {
        float inv = 1.0f / denom;
        float4 b0 = ((const float4*)b1)[l * 2];
        float4 b4 = ((const float4*)b1)[l * 2 + 1];
        float4 r0, r1;
        r0.x = fmaf(ac[0], inv, b0.x); r0.x = r0.x > 0.f ? r0.x : expm1f(r0.x);
        r0.y = fmaf(ac[1], inv, b0.y); r0.y = r0.y > 0.f ? r0.y : expm1f(r0.y);
        r0.z = fmaf(ac[2], inv, b0.z); r0.z = r0.z > 0.f ? r0.z : expm1f(r0.z);
        r0.w = fmaf(ac[3], inv, b0.w); r0.w = r0.w > 0.f ? r0.w : expm1f(r0.w);
        r1.x = fmaf(ac[4], inv, b4.x); r1.x = r1.x > 0.f ? r1.x : expm1f(r1.x);
        r1.y = fmaf(ac[5], inv, b4.y); r1.y = r1.y > 0.f ? r1.y : expm1f(r1.y);
        r1.z = fmaf(ac[6], inv, b4.z); r1.z = r1.z > 0.f ? r1.z : expm1f(r1.z);
        r1.w = fmaf(ac[7], inv, b4.w); r1.w = r1.w > 0.f ? r1.w : expm1f(r1.w);
        ((float4*)out)[d * 16 + l * 2]     = r0;
        ((float4*)out)[d * 16 + l * 2 + 1] = r1;
    }
}

// ===========================================================================
// K5: rec = hin @ W2 (fp8 + a_s2 in 128B records) + a_d2. Register-tiled
// 8x8: 256 nodes/block, K=64 in 2 tiles of 32, LDS 48KB. Overwrites the
// layer-1 records (agg1 already complete; stream-ordered).
// ===========================================================================
__global__ __launch_bounds__(256, 3)
void k_lin2(const float* __restrict__ hin, const float* __restrict__ W2,
            const float* __restrict__ att_s, const float* __restrict__ att_d,
            unsigned int* __restrict__ rec, float* __restrict__ a_d) {
    __shared__ float4 sW4[D1 * 16];      // 16 KB
    __shared__ float sxT[32][256];       // 32 KB
    int tid = threadIdx.x;
    const float4* W4 = (const float4*)W2;
    for (int i = tid; i < D1 * 16; i += 256) sW4[i] = W4[i];
    int node0 = blockIdx.x * 256;
    int rg = tid >> 3, cg = tid & 7;
    float acc[8][8];
#pragma unroll
    for (int ii = 0; ii < 8; ++ii)
#pragma unroll
        for (int jj = 0; jj < 8; ++jj) acc[ii][jj] = 0.f;
    const float4* x4 = (const float4*)hin;
    for (int kt = 0; kt < 2; ++kt) {     // K tiles of 32
        if (kt) __syncthreads();
#pragma unroll
        for (int q = 0; q < 8; ++q) {    // stage 256 rows x 32 k, transposed
            int i = q * 256 + tid;
            int r = i >> 3, kc = i & 7;
            int gn = node0 + r;
            float4 v = {0.f, 0.f, 0.f, 0.f};
            if (gn < NN) v = x4[(size_t)gn * 16 + kt * 8 + kc];
            int cs = r ^ (kc << 3);
            sxT[kc * 4 + 0][cs] = v.x;
            sxT[kc * 4 + 1][cs] = v.y;
            sxT[kc * 4 + 2][cs] = v.z;
            sxT[kc * 4 + 3][cs] = v.w;
        }
        __syncthreads();
#pragma unroll 4
        for (int kk = 0; kk < 32; ++kk) {
            int sw = (kk >> 2) << 3;
            const float* xr = &sxT[kk][(rg * 8) ^ sw];
            float4 xa = *(const float4*)xr;
            float4 xb = *(const float4*)(xr + 4);
            int kg = kt * 32 + kk;
            float4 wa = sW4[kg * 16 + cg * 2];
            float4 wb = sW4[kg * 16 + cg * 2 + 1];
            float xv[8] = {xa.x, xa.y, xa.z, xa.w, xb.x, xb.y, xb.z, xb.w};
            float wv[8] = {wa.x, wa.y, wa.z, wa.w, wb.x, wb.y, wb.z, wb.w};
#pragma unroll
            for (int ii = 0; ii < 8; ++ii)
#pragma unroll
                for (int jj = 0; jj < 8; ++jj)
                    acc[ii][jj] = fmaf(xv[ii], wv[jj], acc[ii][jj]);
        }
    }
    // epilogue: fp8 pack + single-head dots (reduce over 8 cg lanes)
    float4 s0 = ((const float4*)att_s)[cg * 2];
    float4 s1 = ((const float4*)att_s)[cg * 2 + 1];
    float4 d0 = ((const float4*)att_d)[cg * 2];
    float4 d1 = ((const float4*)att_d)[cg * 2 + 1];
    uint2* hp2 = (uint2*)rec;
#pragma unroll
    for (int ii = 0; ii < 8; ++ii) {
        int n = node0 + rg * 8 + ii;
        if (n < NN) {
            float* a = acc[ii];
            int p0 = __builtin_amdgcn_cvt_pk_fp8_f32(a[0], a[1], 0, false);
            p0 = __builtin_amdgcn_cvt_pk_fp8_f32(a[2], a[3], p0, true);
            int p1 = __builtin_amdgcn_cvt_pk_fp8_f32(a[4], a[5], 0, false);
            p1 = __builtin_amdgcn_cvt_pk_fp8_f32(a[6], a[7], p1, true);
            uint2 pk; pk.x = (unsigned)p0; pk.y = (unsigned)p1;
            hp2[n * 16 + cg] = pk;
            float vs = a[0] * s0.x;
            vs = fmaf(a[1], s0.y, vs); vs = fmaf(a[2], s0.z, vs);
            vs = fmaf(a[3], s0.w, vs); vs = fmaf(a[4], s1.x, vs);
            vs = fmaf(a[5], s1.y, vs); vs = fmaf(a[6], s1.z, vs);
            vs = fmaf(a[7], s1.w, vs);
            float vd = a[0] * d0.x;
            vd = fmaf(a[1], d0.y, vd); vd = fmaf(a[2], d0.z, vd);
            vd = fmaf(a[3], d0.w, vd); vd = fmaf(a[4], d1.x, vd);
            vd = fmaf(a[5], d1.y, vd); vd = fmaf(a[6], d1.z, vd);
            vd = fmaf(a[7], d1.w, vd);
            vs += __shfl_xor(vs, 1, 64); vs += __shfl_xor(vs, 2, 64);
            vs += __shfl_xor(vs, 4, 64);
            vd += __shfl_xor(vd, 1, 64); vd += __shfl_xor(vd, 2, 64);
            vd += __shfl_xor(vd, 4, 64);
            if (cg == 0) {
                ((float*)rec)[(size_t)n * 32 + 16] = vs;   // byte offset 64
                a_d[n] = vd;
            }
        }
    }
}

// ===========================================================================
// Agg layer 2 (1 head). Same 2-node/wave pipelined structure; a_s2 read
// from the same 128B record line as the h gather. Fused bias + mean-pool.
// ===========================================================================
__global__ __launch_bounds__(256, 8)
void k_gat_agg2(const int* __restrict__ rbeg, const int* __restrict__ rend,
                const int* __restrict__ col,
                const unsigned int* __restrict__ rec, const float* __restrict__ a_d,
                const float* __restrict__ b2, const int* __restrict__ batch,
                float* __restrict__ pool, float* __restrict__ cnt) {
    __shared__ float sv[8][64];
    __shared__ int sgi[8];
    int wv = threadIdx.x >> 6;
    int lane = threadIdx.x & 63;
    int half = lane >> 5;
    int idx = wv * 2 + half;
    int d = blockIdx.x * 8 + idx;
    int gs = (lane >> 3) & 3;
    int l = lane & 7;
    int rb = rbeg[d], re = rend[d];
    float ad = a_d[d];
    const uint2* hp = (const uint2*)rec;
    const float* recf = (const float*)rec;
    uint2 rself = hp[d * 16 + l];
    float asself = recf[d * 32 + 16];
    if (gs == 0 && l == 0) sgi[idx] = batch[d];
    float ac[8] = {0.f,0.f,0.f,0.f,0.f,0.f,0.f,0.f};
    float denom = 0.f;
    int e = rb + gs;
    int s[4];
#pragma unroll
    for (int q = 0; q < 4; ++q) s[q] = col[e + 4 * q];
    for (; e + 12 < re; ) {
        uint2 rr[4]; float asv[4]; int sn[4];
#pragma unroll
        for (int q = 0; q < 4; ++q) rr[q] = hp[(unsigned)(s[q] * 16 + l)];
#pragma unroll
        for (int q = 0; q < 4; ++q) asv[q] = recf[(unsigned)(s[q] * 32 + 16)];
        int en = e + 16;
#pragma unroll
        for (int q = 0; q < 4; ++q) sn[q] = col[en + 4 * q];
#pragma unroll
        for (int q = 0; q < 4; ++q) {
            float xx = asv[q] + ad;
            xx = xx >= 0.f ? xx : NEG * xx;
            float w = __expf(xx);
            denom += w;
            v2f f0 = __builtin_amdgcn_cvt_pk_f32_fp8((int)rr[q].x, false);
            v2f f1 = __builtin_amdgcn_cvt_pk_f32_fp8((int)rr[q].x, true);
            v2f f2 = __builtin_amdgcn_cvt_pk_f32_fp8((int)rr[q].y, false);
            v2f f3 = __builtin_amdgcn_cvt_pk_f32_fp8((int)rr[q].y, true);
            ac[0] = fmaf(f0.x, w, ac[0]); ac[1] = fmaf(f0.y, w, ac[1]);
            ac[2] = fmaf(f1.x, w, ac[2]); ac[3] = fmaf(f1.y, w, ac[3]);
            ac[4] = fmaf(f2.x, w, ac[4]); ac[5] = fmaf(f2.y, w, ac[5]);
            ac[6] = fmaf(f3.x, w, ac[6]); ac[7] = fmaf(f3.y, w, ac[7]);
        }
        e = en;
#pragma unroll
        for (int q = 0; q < 4; ++q) s[q] = sn[q];
    }
    for (; e < re; e += 4) {
        int s0 = col[e];
        uint2 r0 = hp[(unsigned)(s0 * 16 + l)];
        float x0 = recf[(unsigned)(s0 * 32 + 16)] + ad;
        x0 = x0 >= 0.f ? x0 : NEG * x0;
        float w0 = __expf(x0);
        denom += w0;
        v2f f0 = __builtin_amdgcn_cvt_pk_f32_fp8((int)r0.x, false);
        v2f f1 = __builtin_amdgcn_cvt_pk_f32_fp8((int)r0.x, true);
        v2f f2 = __builtin_amdgcn_cvt_pk_f32_fp8((int)r0.y, false);
        v2f f3 = __builtin_amdgcn_cvt_pk_f32_fp8((int)r0.y, true);
        ac[0] = fmaf(f0.x, w0, ac[0]); ac[1] = fmaf(f0.y, w0, ac[1]);
        ac[2] = fmaf(f1.x, w0, ac[2]); ac[3] = fmaf(f1.y, w0, ac[3]);
        ac[4] = fmaf(f2.x, w0, ac[4]); ac[5] = fmaf(f2.y, w0, ac[5]);
        ac[6] = fmaf(f3.x, w0, ac[6]); ac[7] = fmaf(f3.y, w0, ac[7]);
    }
    if (gs == 0) {
        float es = asself + ad;
        es = es >= 0.f ? es : NEG * es;
        float w = __expf(es);
        denom += w;
        v2f f0 = __builtin_amdgcn_cvt_pk_f32_fp8((int)rself.x, false);
        v2f f1 = __builtin_amdgcn_cvt_pk_f32_fp8((int)rself.x, true);
        v2f f2 = __builtin_amdgcn_cvt_pk_f32_fp8((int)rself.y, false);
        v2f f3 = __builtin_amdgcn_cvt_pk_f32_fp8((int)rself.y, true);
        ac[0] = fmaf(f0.x, w, ac[0]); ac[1] = fmaf(f0.y, w, ac[1]);
        ac[2] = fmaf(f1.x, w, ac[2]); ac[3] = fmaf(f1.y, w, ac[3]);
        ac[4] = fmaf(f2.x, w, ac[4]); ac[5] = fmaf(f2.y, w, ac[5]);
        ac[6] = fmaf(f3.x, w, ac[6]); ac[7] = fmaf(f3.y, w, ac[7]);
    }
#pragma unroll
    for (int i = 0; i < 8; ++i) {
        ac[i] += __shfl_xor(ac[i], 8, 64);
        ac[i] += __shfl_xor(ac[i], 16, 64);
    }
    denom += __shfl_xor(denom, 8, 64);
    denom += __shfl_xor(denom, 16, 64);
    if (gs == 0) {
        float inv = 1.0f / denom;
#pragma unroll
        for (int i = 0; i < 8; ++i)
            sv[idx][l * 8 + i] = fmaf(ac[i], inv, b2[l * 8 + i]);
    }
    __syncthreads();
    int tid = threadIdx.x;
    if (tid < 64) {
        float acc = sv[0][tid]; int curg = sgi[0];
        for (int r = 1; r < 8; ++r) {
            if (sgi[r] == curg) acc += sv[r][tid];
            else { atomicAdd(&pool[curg * 64 + tid], acc); curg = sgi[r]; acc = sv[r][tid]; }
        }
        atomicAdd(&pool[curg * 64 + tid], acc);
    } else if (tid == 64) {
        float c = 1.f; int curg = sgi[0];
        for (int r = 1; r < 8; ++r) {
            if (sgi[r] == curg) c += 1.f;
            else { atomicAdd(&cnt[curg], c); curg = sgi[r]; c = 1.f; }
        }
        atomicAdd(&cnt[curg], c);
    }
}

// K9: g = pool/cnt ; hidden = elu(g@lw1+lb1) ; out = hidden@lw2 + lb2
__global__ __launch_bounds__(128)
void k_mlp(const float* __restrict__ pool, const float* __restrict__ cnt,
           const float* __restrict__ lw1, const float* __restrict__ lb1,
           const float* __restrict__ lw2, const float* __restrict__ lb2,
           float* __restrict__ out) {
    __shared__ float sg[OUTC];
    __shared__ float sh[HID];
    int g = blockIdx.x, tid = threadIdx.x;
    float c = fmaxf(cnt[g], 1.0f);
    if (tid < OUTC) sg[tid] = pool[g * OUTC + tid] / c;
    __syncthreads();
    float acc = lb1[tid];
#pragma unroll 8
    for (int k = 0; k < OUTC; ++k)
        acc = fmaf(sg[k], lw1[k * HID + tid], acc);
    acc = acc > 0.f ? acc : expm1f(acc);
    sh[tid] = acc * lw2[tid];
    __syncthreads();
    for (int off = 64; off >= 1; off >>= 1) {
        if (tid < off) sh[tid] += sh[tid + off];
        __syncthreads();
    }
    if (tid == 0) out[g] = sh[0] + lb2[0];
}

extern "C" void kernel_launch(void* const* d_in, const int* in_sizes, int n_in,
                              void* d_out, int out_size, void* d_ws, size_t ws_size,
                              hipStream_t stream) {
    const float* x    = (const float*)d_in[0];
    const int*   ei   = (const int*)d_in[1];
    const int*   batch= (const int*)d_in[2];
    const float* W1   = (const float*)d_in[3];
    const float* as1  = (const float*)d_in[4];
    const float* ad1  = (const float*)d_in[5];
    const float* b1   = (const float*)d_in[6];
    const float* W2   = (const float*)d_in[7];
    const float* as2  = (const float*)d_in[8];
    const float* ad2  = (const float*)d_in[9];
    const float* b2   = (const float*)d_in[10];
    const float* lw1  = (const float*)d_in[11];
    const float* lb1  = (const float*)d_in[12];
    const float* lw2  = (const float*)d_in[13];
    const float* lb2  = (const float*)d_in[14];
    float* out = (float*)d_out;

    // workspace layout (~60 MB); colv has +1024-int pad for pipelined preloads
    unsigned int* REC = (unsigned int*)d_ws;         // N*32 uints = 128B records (12.8 MB)
    float* B    = (float*)(REC + (size_t)NN * 32);   // N*64 fp32 (25.6 MB)
    float* aD1  = B + (size_t)NN * 64;               // N*8
    float* aD2  = aD1 + (size_t)NN * 8;              // N
    float* pool = aD2 + NN;                          // G*64
    float* cntp = pool + GG * 64;                    // G
    int* rbeg   = (int*)(cntp + GG);                 // N
    int* rend   = rbeg + NN;                         // N
    int* curv   = rend + NN;                         // N
    int* cntn   = curv + NN;                         // BINS*BNODE (400KB)
    int* colv   = cntn + (size_t)BINS * BNODE;       // BINS*BCAP + pad (15MB)

    const int* srcv = ei;
    const int* dstv = ei + EE;

    hipMemsetAsync(cntn, 0, (size_t)BINS * BNODE * sizeof(int), stream);
    hipMemsetAsync(pool, 0, (size_t)(GG * 64 + GG) * sizeof(float), stream);

    // FUSED: lin1 GEMM (391 long blocks, first) + degree count (1563 short)
    k_fused<<<NGB + BKBLK, 256, 0, stream>>>(dstv, cntn,
                                             x, W1, as1, ad1, REC, aD1);
    // per-bin scan -> rbeg/rend/cur; then direct scatter into col
    k_scan   <<<BINS, 128, 0, stream>>>(cntn, rbeg, rend, curv);
    k_scatter<<<BKBLK, 256, 0, stream>>>(srcv, dstv, curv, colv);

    // layer 1 aggregation
    k_gat_agg1<<<NN / 8, 256, 0, stream>>>(rbeg, rend, colv, REC, aD1, b1, B);

    // layer 2 (lin2 overwrites REC with layer-2 records; stream-ordered)
    k_lin2    <<<NGB, 256, 0, stream>>>(B, W2, as2, ad2, REC, aD2);
    k_gat_agg2<<<NN / 8, 256, 0, stream>>>(rbeg, rend, colv, REC, aD2, b2, batch, pool, cntp);

    // MLP head
    k_mlp<<<GG, 128, 0, stream>>>(pool, cntp, lw1, lb1, lw2, lb2, out);
}

// Round 8
// 463.601 us; speedup vs baseline: 1.4829x; 1.4829x over previous
//
#include <hip/hip_runtime.h>
#include <hip/hip_fp16.h>
#include <math.h>

// Problem constants (match reference)
#define NN   100000
#define EE   3200000
#define GG   512
#define INC  128
#define D1   64        // H1*C1 = 8*8
#define OUTC 64
#define HID  128
#define NEG  0.2f

// Two-level CSR binning: 128-node bins
#define BINS   782     // ceil(NN/128)
#define BNODE  128
#define BSHIFT 7
#define BMASK  127
#define BCAP   4800    // Binomial mean 4096 + 11 sigma; overflow-guarded
#define BKBLK 1563     // ceil(EE/2048) bucket blocks in the fused kernel
#define NGB 391        // ceil(NN/256) register-tiled GEMM blocks

typedef __attribute__((ext_vector_type(2))) float v2f;

// Node record layout (both layers, shared buffer REC, 128B/node aligned):
//   bytes  0..63 : 64 x fp8 h-row
//   bytes 64..79 : layer1: 8 x half a_src   | layer2: float a_src at byte 64
//   bytes 80..127: pad

// ===========================================================================
// FUSED: [blocks 0..NGB) = lin1 GEMM  |  [NGB..) = bucket scatter.
// R7: W1 staged PER K-TILE (4KB, L2-hot reload) instead of 32KB resident ->
// LDS 48KB -> 20KB -> 6 blocks/CU (was 3). The latency-bound scatter branch
// gets 24 waves/CU (was 12): R5 showed k_fused at 25% occupancy with no
// saturated pipe -> occupancy was the limiter.
// ===========================================================================
__global__ __launch_bounds__(256, 6)
void k_fused(const int* __restrict__ srcv, const int* __restrict__ dstv,
             int* __restrict__ cursor, int* __restrict__ bucket,
             const float* __restrict__ x, const float* __restrict__ W1,
             const float* __restrict__ att_s, const float* __restrict__ att_d,
             unsigned int* __restrict__ rec, float* __restrict__ a_d) {
    __shared__ __align__(16) char smem[20480];
    int tid = threadIdx.x;
    if (blockIdx.x < NGB) {
        // ---------------- lin1: rec = x @ W1 (fp8 + a_s), attention dots ---
        float4* sWt = (float4*)smem;                        // 4096 B: 16 k-rows
        float (*sxT)[256] = (float(*)[256])(smem + 4096);   // 16384 B
        const float4* W4 = (const float4*)W1;
        int node0 = blockIdx.x * 256;
        int rg = tid >> 3, cg = tid & 7;     // 32 row-groups x 8 col-groups
        float acc[8][8];
#pragma unroll
        for (int ii = 0; ii < 8; ++ii)
#pragma unroll
            for (int jj = 0; jj < 8; ++jj) acc[ii][jj] = 0.f;
        const float4* x4 = (const float4*)x;
        for (int kt = 0; kt < 8; ++kt) {     // K tiles of 16
            if (kt) __syncthreads();         // readers done with prev tile
            sWt[tid] = W4[kt * 256 + tid];   // stage 16 W rows (4KB; L2-hot)
#pragma unroll
            for (int q = 0; q < 4; ++q) {    // stage 256 rows x 16 k, transposed
                int i = q * 256 + tid;
                int r = i >> 2, kc = i & 3;
                int gn = node0 + r;
                float4 v = {0.f, 0.f, 0.f, 0.f};
                if (gn < NN) v = x4[(size_t)gn * 32 + kt * 4 + kc];
                int cs = r ^ (kc << 3);      // swizzle: s = (k>>2)<<3, k>>2 = kc
                sxT[kc * 4 + 0][cs] = v.x;
                sxT[kc * 4 + 1][cs] = v.y;
                sxT[kc * 4 + 2][cs] = v.z;
                sxT[kc * 4 + 3][cs] = v.w;
            }
            __syncthreads();
#pragma unroll 4
            for (int kk = 0; kk < 16; ++kk) {
                int sw = (kk >> 2) << 3;
                const float* xr = &sxT[kk][(rg * 8) ^ sw];
                float4 xa = *(const float4*)xr;
                float4 xb = *(const float4*)(xr + 4);
                float4 wa = sWt[kk * 16 + cg * 2];
                float4 wb = sWt[kk * 16 + cg * 2 + 1];
                float xv[8] = {xa.x, xa.y, xa.z, xa.w, xb.x, xb.y, xb.z, xb.w};
                float wv[8] = {wa.x, wa.y, wa.z, wa.w, wb.x, wb.y, wb.z, wb.w};
#pragma unroll
                for (int ii = 0; ii < 8; ++ii)
#pragma unroll
                    for (int jj = 0; jj < 8; ++jj)
                        acc[ii][jj] = fmaf(xv[ii], wv[jj], acc[ii][jj]);
            }
        }
        // epilogue: fp8 pack + per-head attention dots (head == cg, no reduce)
        float4 s0 = ((const float4*)att_s)[cg * 2];
        float4 s1 = ((const float4*)att_s)[cg * 2 + 1];
        float4 d0 = ((const float4*)att_d)[cg * 2];
        float4 d1 = ((const float4*)att_d)[cg * 2 + 1];
        uint2* hp2 = (uint2*)rec;
        __half* ash = (__half*)rec;
#pragma unroll
        for (int ii = 0; ii < 8; ++ii) {
            int n = node0 + rg * 8 + ii;
            if (n < NN) {
                float* a = acc[ii];
                int p0 = __builtin_amdgcn_cvt_pk_fp8_f32(a[0], a[1], 0, false);
                p0 = __builtin_amdgcn_cvt_pk_fp8_f32(a[2], a[3], p0, true);
                int p1 = __builtin_amdgcn_cvt_pk_fp8_f32(a[4], a[5], 0, false);
                p1 = __builtin_amdgcn_cvt_pk_fp8_f32(a[6], a[7], p1, true);
                uint2 pk; pk.x = (unsigned)p0; pk.y = (unsigned)p1;
                hp2[n * 16 + cg] = pk;       // record stride 128B = 16 uint2
                float as = a[0] * s0.x;
                as = fmaf(a[1], s0.y, as); as = fmaf(a[2], s0.z, as);
                as = fmaf(a[3], s0.w, as); as = fmaf(a[4], s1.x, as);
                as = fmaf(a[5], s1.y, as); as = fmaf(a[6], s1.z, as);
                as = fmaf(a[7], s1.w, as);
                float ad = a[0] * d0.x;
                ad = fmaf(a[1], d0.y, ad); ad = fmaf(a[2], d0.z, ad);
                ad = fmaf(a[3], d0.w, ad); ad = fmaf(a[4], d1.x, ad);
                ad = fmaf(a[5], d1.y, ad); ad = fmaf(a[6], d1.z, ad);
                ad = fmaf(a[7], d1.w, ad);
                ash[n * 64 + 32 + cg] = __float2half(as);   // byte 64 + 2*cg
                a_d[n * 8 + cg] = ad;
            }
        }
    } else {
        // ---------------- bucket scatter (128-node bins) ----------------
        int* hcnt  = (int*)smem;          // BINS (3128B)
        int* hbase = hcnt + BINS;         // BINS
        for (int i = tid; i < BINS; i += 256) hcnt[i] = 0;
        __syncthreads();
        int e0 = (blockIdx.x - NGB) * 2048;
        int bn[8], rk[8], pk[8];
#pragma unroll
        for (int q = 0; q < 8; ++q) {
            int e = e0 + q * 256 + tid;
            if (e < EE) {
                int s = srcv[e], d = dstv[e];
                bn[q] = d >> BSHIFT;
                pk[q] = (s << BSHIFT) | (d & BMASK);
                rk[q] = atomicAdd(&hcnt[bn[q]], 1);   // LDS atomic
            } else bn[q] = -1;
        }
        __syncthreads();
        for (int i = tid; i < BINS; i += 256) {
            int c = hcnt[i];
            hbase[i] = c ? atomicAdd(&cursor[i], c) : 0;
        }
        __syncthreads();
#pragma unroll
        for (int q = 0; q < 8; ++q) {
            if (bn[q] >= 0) {
                int p = hbase[bn[q]] + rk[q];
                if (p < BCAP) bucket[bn[q] * BCAP + p] = pk[q];
            }
        }
    }
}

// ===========================================================================
// P3: per-bin fine CSR, SINGLE-PASS: bin segment cached in LDS during the
// histogram read; scatter pass reads LDS (no second global walk of bucket).
// One block per 128-node bin.
// ===========================================================================
__global__ __launch_bounds__(256)
void k_binCSR(const int* __restrict__ cursor, const int* __restrict__ bucket,
              int* __restrict__ col, int* __restrict__ rbeg, int* __restrict__ rend) {
    __shared__ int sseg[BCAP];           // 19200 B
    __shared__ int cnt_[BNODE];
    __shared__ int tmp[BNODE];
    __shared__ int cur[BNODE];
    int b = blockIdx.x, tid = threadIdx.x;
    if (tid < BNODE) cnt_[tid] = 0;
    __syncthreads();
    int m = cursor[b]; if (m > BCAP) m = BCAP;
    const int* seg = bucket + b * BCAP;
    for (int i = tid; i < m; i += 256) {
        int v = seg[i];
        sseg[i] = v;
        atomicAdd(&cnt_[v & BMASK], 1);
    }
    __syncthreads();
    if (tid < BNODE) tmp[tid] = cnt_[tid];
    __syncthreads();
    for (int off = 1; off < BNODE; off <<= 1) {
        int t = (tid >= off && tid < BNODE) ? tmp[tid - off] : 0;
        __syncthreads();
        if (tid < BNODE) tmp[tid] += t;
        __syncthreads();
    }
    if (tid < BNODE) {
        int excl = tmp[tid] - cnt_[tid];
        int n = b * BNODE + tid;
        if (n < NN) {
            rbeg[n] = b * BCAP + excl;
            rend[n] = b * BCAP + excl + cnt_[tid];
        }
        cur[tid] = excl;
    }
    __syncthreads();
    for (int i = tid; i < m; i += 256) {
        int pkv = sseg[i];
        int r = atomicAdd(&cur[pkv & BMASK], 1);
        col[b * BCAP + r] = pkv >> BSHIFT;
    }
}

// ===========================================================================
// Agg layer 1 (8 heads). Wave = 2 nodes x (4 edge-slots x 8 lanes), lane&7 =
// head = ch-group (uint2 fp8 row slice). 1-deep index prefetch (pad-safe).
// a_src read from the SAME 128B record line as the h gather.
// ===========================================================================
__global__ __launch_bounds__(256, 8)
void k_gat_agg1(const int* __restrict__ rbeg, const int* __restrict__ rend,
                const int* __restrict__ col,
                const unsigned int* __restrict__ rec, const float* __restrict__ a_d,
                const float* __restrict__ b1, float* __restrict__ out) {
    int wv = threadIdx.x >> 6;
    int lane = threadIdx.x & 63;
    int half = lane >> 5;
    int d = blockIdx.x * 8 + wv * 2 + half;
    int gs = (lane >> 3) & 3;   // slot within node
    int l = lane & 7;           // head / ch-group
    int rb = rbeg[d], re = rend[d];
    float adh = a_d[d * 8 + l];
    const uint2* hp = (const uint2*)rec;
    const __half* asr = (const __half*)rec;
    uint2 rself = hp[d * 16 + l];
    float asself = __half2float(asr[d * 64 + 32 + l]);
    float ac[8] = {0.f,0.f,0.f,0.f,0.f,0.f,0.f,0.f};
    float denom = 0.f;
    int e = rb + gs;
    int s[4];
#pragma unroll
    for (int q = 0; q < 4; ++q) s[q] = col[e + 4 * q];   // pad-safe preload
    for (; e + 12 < re; ) {
        uint2 rr[4]; float asv[4]; int sn[4];
#pragma unroll
        for (int q = 0; q < 4; ++q) rr[q] = hp[(unsigned)(s[q] * 16 + l)];
#pragma unroll
        for (int q = 0; q < 4; ++q) asv[q] = __half2float(asr[(unsigned)(s[q] * 64 + 32 + l)]);
        int en = e + 16;
#pragma unroll
        for (int q = 0; q < 4; ++q) sn[q] = col[en + 4 * q];  // prefetch next
#pragma unroll
        for (int q = 0; q < 4; ++q) {
            float xx = asv[q] + adh;
            xx = xx >= 0.f ? xx : NEG * xx;
            float w = __expf(xx);
            denom += w;
            v2f f0 = __builtin_amdgcn_cvt_pk_f32_fp8((int)rr[q].x, false);
            v2f f1 = __builtin_amdgcn_cvt_pk_f32_fp8((int)rr[q].x, true);
            v2f f2 = __builtin_amdgcn_cvt_pk_f32_fp8((int)rr[q].y, false);
            v2f f3 = __builtin_amdgcn_cvt_pk_f32_fp8((int)rr[q].y, true);
            ac[0] = fmaf(f0.x, w, ac[0]); ac[1] = fmaf(f0.y, w, ac[1]);
            ac[2] = fmaf(f1.x, w, ac[2]); ac[3] = fmaf(f1.y, w, ac[3]);
            ac[4] = fmaf(f2.x, w, ac[4]); ac[5] = fmaf(f2.y, w, ac[5]);
            ac[6] = fmaf(f3.x, w, ac[6]); ac[7] = fmaf(f3.y, w, ac[7]);
        }
        e = en;
#pragma unroll
        for (int q = 0; q < 4; ++q) s[q] = sn[q];
    }
    for (; e < re; e += 4) {
        int s0 = col[e];
        uint2 r0 = hp[(unsigned)(s0 * 16 + l)];
        float x0 = __half2float(asr[(unsigned)(s0 * 64 + 32 + l)]) + adh;
        x0 = x0 >= 0.f ? x0 : NEG * x0;
        float w0 = __expf(x0);
        denom += w0;
        v2f f0 = __builtin_amdgcn_cvt_pk_f32_fp8((int)r0.x, false);
        v2f f1 = __builtin_amdgcn_cvt_pk_f32_fp8((int)r0.x, true);
        v2f f2 = __builtin_amdgcn_cvt_pk_f32_fp8((int)r0.y, false);
        v2f f3 = __builtin_amdgcn_cvt_pk_f32_fp8((int)r0.y, true);
        ac[0] = fmaf(f0.x, w0, ac[0]); ac[1] = fmaf(f0.y, w0, ac[1]);
        ac[2] = fmaf(f1.x, w0, ac[2]); ac[3] = fmaf(f1.y, w0, ac[3]);
        ac[4] = fmaf(f2.x, w0, ac[4]); ac[5] = fmaf(f2.y, w0, ac[5]);
        ac[6] = fmaf(f3.x, w0, ac[6]); ac[7] = fmaf(f3.y, w0, ac[7]);
    }
    if (gs == 0) {      // self-loop contribution
        float es = asself + adh;
        es = es >= 0.f ? es : NEG * es;
        float w = __expf(es);
        denom += w;
        v2f f0 = __builtin_amdgcn_cvt_pk_f32_fp8((int)rself.x, false);
        v2f f1 = __builtin_amdgcn_cvt_pk_f32_fp8((int)rself.x, true);
        v2f f2 = __builtin_amdgcn_cvt_pk_f32_fp8((int)rself.y, false);
        v2f f3 = __builtin_amdgcn_cvt_pk_f32_fp8((int)rself.y, true);
        ac[0] = fmaf(f0.x, w, ac[0]); ac[1] = fmaf(f0.y, w, ac[1]);
        ac[2] = fmaf(f1.x, w, ac[2]); ac[3] = fmaf(f1.y, w, ac[3]);
        ac[4] = fmaf(f2.x, w, ac[4]); ac[5] = fmaf(f2.y, w, ac[5]);
        ac[6] = fmaf(f3.x, w, ac[6]); ac[7] = fmaf(f3.y, w, ac[7]);
    }
#pragma unroll
    for (int i = 0; i < 8; ++i) {     // reduce 4 slots (stays within 32-half)
        ac[i] += __shfl_xor(ac[i], 8, 64);
        ac[i] += __shfl_xor(ac[i], 16, 64);
    }
    denom += __shfl_xor(denom, 8, 64);
    denom += __shfl_xor(denom, 16, 64);
    if (gs == 0) {
        float inv = 1.0f / denom;
        float4 b0 = ((const float4*)b1)[l * 2];
        float4 b4 = ((const float4*)b1)[l * 2 + 1];
        float4 r0, r1;
        r0.x = fmaf(ac[0], inv, b0.x); r0.x = r0.x > 0.f ? r0.x : expm1f(r0.x);
        r0.y = fmaf(ac[1], inv, b0.y); r0.y = r0.y > 0.f ? r0.y : expm1f(r0.y);
        r0.z = fmaf(ac[2], inv, b0.z); r0.z = r0.z > 0.f ? r0.z : expm1f(r0.z);
        r0.w = fmaf(ac[3], inv, b0.w); r0.w = r0.w > 0.f ? r0.w : expm1f(r0.w);
        r1.x = fmaf(ac[4], inv, b4.x); r1.x = r1.x > 0.f ? r1.x : expm1f(r1.x);
        r1.y = fmaf(ac[5], inv, b4.y); r1.y = r1.y > 0.f ? r1.y : expm1f(r1.y);
        r1.z = fmaf(ac[6], inv, b4.z); r1.z = r1.z > 0.f ? r1.z : expm1f(r1.z);
        r1.w = fmaf(ac[7], inv, b4.w); r1.w = r1.w > 0.f ? r1.w : expm1f(r1.w);
        ((float4*)out)[d * 16 + l * 2]     = r0;
        ((float4*)out)[d * 16 + l * 2 + 1] = r1;
    }
}

// ===========================================================================
// K5: rec = hin @ W2 (fp8 + a_s2 in 128B records) + a_d2. Register-tiled
// 8x8: 256 nodes/block, K=64 in 2 tiles of 32, LDS 48KB. Overwrites the
// layer-1 records (agg1 already complete; stream-ordered).
// ===========================================================================
__global__ __launch_bounds__(256, 3)
void k_lin2(const float* __restrict__ hin, const float* __restrict__ W2,
            const float* __restrict__ att_s, const float* __restrict__ att_d,
            unsigned int* __restrict__ rec, float* __restrict__ a_d) {
    __shared__ float4 sW4[D1 * 16];      // 16 KB
    __shared__ float sxT[32][256];       // 32 KB
    int tid = threadIdx.x;
    const float4* W4 = (const float4*)W2;
    for (int i = tid; i < D1 * 16; i += 256) sW4[i] = W4[i];
    int node0 = blockIdx.x * 256;
    int rg = tid >> 3, cg = tid & 7;
    float acc[8][8];
#pragma unroll
    for (int ii = 0; ii < 8; ++ii)
#pragma unroll
        for (int jj = 0; jj < 8; ++jj) acc[ii][jj] = 0.f;
    const float4* x4 = (const float4*)hin;
    for (int kt = 0; kt < 2; ++kt) {     // K tiles of 32
        if (kt) __syncthreads();
#pragma unroll
        for (int q = 0; q < 8; ++q) {    // stage 256 rows x 32 k, transposed
            int i = q * 256 + tid;
            int r = i >> 3, kc = i & 7;
            int gn = node0 + r;
            float4 v = {0.f, 0.f, 0.f, 0.f};
            if (gn < NN) v = x4[(size_t)gn * 16 + kt * 8 + kc];
            int cs = r ^ (kc << 3);
            sxT[kc * 4 + 0][cs] = v.x;
            sxT[kc * 4 + 1][cs] = v.y;
            sxT[kc * 4 + 2][cs] = v.z;
            sxT[kc * 4 + 3][cs] = v.w;
        }
        __syncthreads();
#pragma unroll 4
        for (int kk = 0; kk < 32; ++kk) {
            int sw = (kk >> 2) << 3;
            const float* xr = &sxT[kk][(rg * 8) ^ sw];
            float4 xa = *(const float4*)xr;
            float4 xb = *(const float4*)(xr + 4);
            int kg = kt * 32 + kk;
            float4 wa = sW4[kg * 16 + cg * 2];
            float4 wb = sW4[kg * 16 + cg * 2 + 1];
            float xv[8] = {xa.x, xa.y, xa.z, xa.w, xb.x, xb.y, xb.z, xb.w};
            float wv[8] = {wa.x, wa.y, wa.z, wa.w, wb.x, wb.y, wb.z, wb.w};
#pragma unroll
            for (int ii = 0; ii < 8; ++ii)
#pragma unroll
                for (int jj = 0; jj < 8; ++jj)
                    acc[ii][jj] = fmaf(xv[ii], wv[jj], acc[ii][jj]);
        }
    }
    // epilogue: fp8 pack + single-head dots (reduce over 8 cg lanes)
    float4 s0 = ((const float4*)att_s)[cg * 2];
    float4 s1 = ((const float4*)att_s)[cg * 2 + 1];
    float4 d0 = ((const float4*)att_d)[cg * 2];
    float4 d1 = ((const float4*)att_d)[cg * 2 + 1];
    uint2* hp2 = (uint2*)rec;
#pragma unroll
    for (int ii = 0; ii < 8; ++ii) {
        int n = node0 + rg * 8 + ii;
        if (n < NN) {
            float* a = acc[ii];
            int p0 = __builtin_amdgcn_cvt_pk_fp8_f32(a[0], a[1], 0, false);
            p0 = __builtin_amdgcn_cvt_pk_fp8_f32(a[2], a[3], p0, true);
            int p1 = __builtin_amdgcn_cvt_pk_fp8_f32(a[4], a[5], 0, false);
            p1 = __builtin_amdgcn_cvt_pk_fp8_f32(a[6], a[7], p1, true);
            uint2 pk; pk.x = (unsigned)p0; pk.y = (unsigned)p1;
            hp2[n * 16 + cg] = pk;
            float vs = a[0] * s0.x;
            vs = fmaf(a[1], s0.y, vs); vs = fmaf(a[2], s0.z, vs);
            vs = fmaf(a[3], s0.w, vs); vs = fmaf(a[4], s1.x, vs);
            vs = fmaf(a[5], s1.y, vs); vs = fmaf(a[6], s1.z, vs);
            vs = fmaf(a[7], s1.w, vs);
            float vd = a[0] * d0.x;
            vd = fmaf(a[1], d0.y, vd); vd = fmaf(a[2], d0.z, vd);
            vd = fmaf(a[3], d0.w, vd); vd = fmaf(a[4], d1.x, vd);
            vd = fmaf(a[5], d1.y, vd); vd = fmaf(a[6], d1.z, vd);
            vd = fmaf(a[7], d1.w, vd);
            vs += __shfl_xor(vs, 1, 64); vs += __shfl_xor(vs, 2, 64);
            vs += __shfl_xor(vs, 4, 64);
            vd += __shfl_xor(vd, 1, 64); vd += __shfl_xor(vd, 2, 64);
            vd += __shfl_xor(vd, 4, 64);
            if (cg == 0) {
                ((float*)rec)[(size_t)n * 32 + 16] = vs;   // byte offset 64
                a_d[n] = vd;
            }
        }
    }
}

// ===========================================================================
// Agg layer 2 (1 head). Same 2-node/wave pipelined structure; a_s2 read
// from the same 128B record line as the h gather. Fused bias + mean-pool.
// ===========================================================================
__global__ __launch_bounds__(256, 8)
void k_gat_agg2(const int* __restrict__ rbeg, const int* __restrict__ rend,
                const int* __restrict__ col,
                const unsigned int* __restrict__ rec, const float* __restrict__ a_d,
                const float* __restrict__ b2, const int* __restrict__ batch,
                float* __restrict__ pool, float* __restrict__ cnt) {
    __shared__ float sv[8][64];
    __shared__ int sgi[8];
    int wv = threadIdx.x >> 6;
    int lane = threadIdx.x & 63;
    int half = lane >> 5;
    int idx = wv * 2 + half;
    int d = blockIdx.x * 8 + idx;
    int gs = (lane >> 3) & 3;
    int l = lane & 7;
    int rb = rbeg[d], re = rend[d];
    float ad = a_d[d];
    const uint2* hp = (const uint2*)rec;
    const float* recf = (const float*)rec;
    uint2 rself = hp[d * 16 + l];
    float asself = recf[d * 32 + 16];
    if (gs == 0 && l == 0) sgi[idx] = batch[d];
    float ac[8] = {0.f,0.f,0.f,0.f,0.f,0.f,0.f,0.f};
    float denom = 0.f;
    int e = rb + gs;
    int s[4];
#pragma unroll
    for (int q = 0; q < 4; ++q) s[q] = col[e + 4 * q];
    for (; e + 12 < re; ) {
        uint2 rr[4]; float asv[4]; int sn[4];
#pragma unroll
        for (int q = 0; q < 4; ++q) rr[q] = hp[(unsigned)(s[q] * 16 + l)];
#pragma unroll
        for (int q = 0; q < 4; ++q) asv[q] = recf[(unsigned)(s[q] * 32 + 16)];
        int en = e + 16;
#pragma unroll
        for (int q = 0; q < 4; ++q) sn[q] = col[en + 4 * q];
#pragma unroll
        for (int q = 0; q < 4; ++q) {
            float xx = asv[q] + ad;
            xx = xx >= 0.f ? xx : NEG * xx;
            float w = __expf(xx);
            denom += w;
            v2f f0 = __builtin_amdgcn_cvt_pk_f32_fp8((int)rr[q].x, false);
            v2f f1 = __builtin_amdgcn_cvt_pk_f32_fp8((int)rr[q].x, true);
            v2f f2 = __builtin_amdgcn_cvt_pk_f32_fp8((int)rr[q].y, false);
            v2f f3 = __builtin_amdgcn_cvt_pk_f32_fp8((int)rr[q].y, true);
            ac[0] = fmaf(f0.x, w, ac[0]); ac[1] = fmaf(f0.y, w, ac[1]);
            ac[2] = fmaf(f1.x, w, ac[2]); ac[3] = fmaf(f1.y, w, ac[3]);
            ac[4] = fmaf(f2.x, w, ac[4]); ac[5] = fmaf(f2.y, w, ac[5]);
            ac[6] = fmaf(f3.x, w, ac[6]); ac[7] = fmaf(f3.y, w, ac[7]);
        }
        e = en;
#pragma unroll
        for (int q = 0; q < 4; ++q) s[q] = sn[q];
    }
    for (; e < re; e += 4) {
        int s0 = col[e];
        uint2 r0 = hp[(unsigned)(s0 * 16 + l)];
        float x0 = recf[(unsigned)(s0 * 32 + 16)] + ad;
        x0 = x0 >= 0.f ? x0 : NEG * x0;
        float w0 = __expf(x0);
        denom += w0;
        v2f f0 = __builtin_amdgcn_cvt_pk_f32_fp8((int)r0.x, false);
        v2f f1 = __builtin_amdgcn_cvt_pk_f32_fp8((int)r0.x, true);
        v2f f2 = __builtin_amdgcn_cvt_pk_f32_fp8((int)r0.y, false);
        v2f f3 = __builtin_amdgcn_cvt_pk_f32_fp8((int)r0.y, true);
        ac[0] = fmaf(f0.x, w0, ac[0]); ac[1] = fmaf(f0.y, w0, ac[1]);
        ac[2] = fmaf(f1.x, w0, ac[2]); ac[3] = fmaf(f1.y, w0, ac[3]);
        ac[4] = fmaf(f2.x, w0, ac[4]); ac[5] = fmaf(f2.y, w0, ac[5]);
        ac[6] = fmaf(f3.x, w0, ac[6]); ac[7] = fmaf(f3.y, w0, ac[7]);
    }
    if (gs == 0) {
        float es = asself + ad;
        es = es >= 0.f ? es : NEG * es;
        float w = __expf(es);
        denom += w;
        v2f f0 = __builtin_amdgcn_cvt_pk_f32_fp8((int)rself.x, false);
        v2f f1 = __builtin_amdgcn_cvt_pk_f32_fp8((int)rself.x, true);
        v2f f2 = __builtin_amdgcn_cvt_pk_f32_fp8((int)rself.y, false);
        v2f f3 = __builtin_amdgcn_cvt_pk_f32_fp8((int)rself.y, true);
        ac[0] = fmaf(f0.x, w, ac[0]); ac[1] = fmaf(f0.y, w, ac[1]);
        ac[2] = fmaf(f1.x, w, ac[2]); ac[3] = fmaf(f1.y, w, ac[3]);
        ac[4] = fmaf(f2.x, w, ac[4]); ac[5] = fmaf(f2.y, w, ac[5]);
        ac[6] = fmaf(f3.x, w, ac[6]); ac[7] = fmaf(f3.y, w, ac[7]);
    }
#pragma unroll
    for (int i = 0; i < 8; ++i) {
        ac[i] += __shfl_xor(ac[i], 8, 64);
        ac[i] += __shfl_xor(ac[i], 16, 64);
    }
    denom += __shfl_xor(denom, 8, 64);
    denom += __shfl_xor(denom, 16, 64);
    if (gs == 0) {
        float inv = 1.0f / denom;
#pragma unroll
        for (int i = 0; i < 8; ++i)
            sv[idx][l * 8 + i] = fmaf(ac[i], inv, b2[l * 8 + i]);
    }
    __syncthreads();
    int tid = threadIdx.x;
    if (tid < 64) {
        float acc = sv[0][tid]; int curg = sgi[0];
        for (int r = 1; r < 8; ++r) {
            if (sgi[r] == curg) acc += sv[r][tid];
            else { atomicAdd(&pool[curg * 64 + tid], acc); curg = sgi[r]; acc = sv[r][tid]; }
        }
        atomicAdd(&pool[curg * 64 + tid], acc);
    } else if (tid == 64) {
        float c = 1.f; int curg = sgi[0];
        for (int r = 1; r < 8; ++r) {
            if (sgi[r] == curg) c += 1.f;
            else { atomicAdd(&cnt[curg], c); curg = sgi[r]; c = 1.f; }
        }
        atomicAdd(&cnt[curg], c);
    }
}

// K9: g = pool/cnt ; hidden = elu(g@lw1+lb1) ; out = hidden@lw2 + lb2
__global__ __launch_bounds__(128)
void k_mlp(const float* __restrict__ pool, const float* __restrict__ cnt,
           const float* __restrict__ lw1, const float* __restrict__ lb1,
           const float* __restrict__ lw2, const float* __restrict__ lb2,
           float* __restrict__ out) {
    __shared__ float sg[OUTC];
    __shared__ float sh[HID];
    int g = blockIdx.x, tid = threadIdx.x;
    float c = fmaxf(cnt[g], 1.0f);
    if (tid < OUTC) sg[tid] = pool[g * OUTC + tid] / c;
    __syncthreads();
    float acc = lb1[tid];
#pragma unroll 8
    for (int k = 0; k < OUTC; ++k)
        acc = fmaf(sg[k], lw1[k * HID + tid], acc);
    acc = acc > 0.f ? acc : expm1f(acc);
    sh[tid] = acc * lw2[tid];
    __syncthreads();
    for (int off = 64; off >= 1; off >>= 1) {
        if (tid < off) sh[tid] += sh[tid + off];
        __syncthreads();
    }
    if (tid == 0) out[g] = sh[0] + lb2[0];
}

extern "C" void kernel_launch(void* const* d_in, const int* in_sizes, int n_in,
                              void* d_out, int out_size, void* d_ws, size_t ws_size,
                              hipStream_t stream) {
    const float* x    = (const float*)d_in[0];
    const int*   ei   = (const int*)d_in[1];
    const int*   batch= (const int*)d_in[2];
    const float* W1   = (const float*)d_in[3];
    const float* as1  = (const float*)d_in[4];
    const float* ad1  = (const float*)d_in[5];
    const float* b1   = (const float*)d_in[6];
    const float* W2   = (const float*)d_in[7];
    const float* as2  = (const float*)d_in[8];
    const float* ad2  = (const float*)d_in[9];
    const float* b2   = (const float*)d_in[10];
    const float* lw1  = (const float*)d_in[11];
    const float* lb1  = (const float*)d_in[12];
    const float* lw2  = (const float*)d_in[13];
    const float* lb2  = (const float*)d_in[14];
    float* out = (float*)d_out;

    // workspace layout (~73 MB); colv has +1024-int pad for pipelined preloads
    unsigned int* REC = (unsigned int*)d_ws;         // N*32 uints = 128B records (12.8 MB)
    float* B    = (float*)(REC + (size_t)NN * 32);   // N*64 fp32 (25.6 MB)
    float* aD1  = B + (size_t)NN * 64;               // N*8
    float* aD2  = aD1 + (size_t)NN * 8;              // N
    float* pool = aD2 + NN;                          // G*64
    float* cntp = pool + GG * 64;                    // G
    int* rbeg   = (int*)(cntp + GG);                 // N
    int* rend   = rbeg + NN;                         // N
    int* cursor = rend + NN;                         // BINS
    int* bucket = cursor + BINS;                     // BINS*BCAP (15.0 MB)
    int* colv   = bucket + (size_t)BINS * BCAP;      // BINS*BCAP + pad

    const int* srcv = ei;
    const int* dstv = ei + EE;

    hipMemsetAsync(cursor, 0, BINS * sizeof(int), stream);
    hipMemsetAsync(pool, 0, (size_t)(GG * 64 + GG) * sizeof(float), stream);

    // FUSED: lin1 GEMM (391 long blocks, first) + bucket scatter (1563 short)
    k_fused<<<NGB + BKBLK, 256, 0, stream>>>(srcv, dstv, cursor, bucket,
                                             x, W1, as1, ad1, REC, aD1);
    k_binCSR<<<BINS, 256, 0, stream>>>(cursor, bucket, colv, rbeg, rend);

    // layer 1 aggregation
    k_gat_agg1<<<NN / 8, 256, 0, stream>>>(rbeg, rend, colv, REC, aD1, b1, B);

    // layer 2 (lin2 overwrites REC with layer-2 records; stream-ordered)
    k_lin2    <<<NGB, 256, 0, stream>>>(B, W2, as2, ad2, REC, aD2);
    k_gat_agg2<<<NN / 8, 256, 0, stream>>>(rbeg, rend, colv, REC, aD2, b2, batch, pool, cntp);

    // MLP head
    k_mlp<<<GG, 128, 0, stream>>>(pool, cntp, lw1, lb1, lw2, lb2, out);
}

// Round 9
// 368.812 us; speedup vs baseline: 1.8640x; 1.2570x over previous
//
#include <hip/hip_runtime.h>
#include <hip/hip_fp16.h>
#include <math.h>

// Problem constants (match reference)
#define NN   100000
#define EE   3200000
#define GG   512
#define INC  128
#define D1   64        // H1*C1 = 8*8
#define OUTC 64
#define HID  128
#define NEG  0.2f

// Two-level CSR binning: 128-node bins
#define BINS   782     // ceil(NN/128)
#define BNODE  128
#define BSHIFT 7
#define BMASK  127
#define BCAP   4800    // Binomial mean 4096 + 11 sigma; overflow-guarded
#define BKBLK 1563     // ceil(EE/2048) bucket blocks in the fused kernel
#define NGB 391        // ceil(NN/256) register-tiled GEMM blocks

typedef __attribute__((ext_vector_type(2))) float v2f;

// Node record layout (both layers, shared buffer REC, 128B/node aligned):
//   bytes  0..63 : 64 x fp8 h-row
//   bytes 64..79 : layer1: 8 x half a_src   | layer2: float a_src at byte 64
//   bytes 80..127: pad

// ===========================================================================
// FUSED: [blocks 0..NGB) = lin1 GEMM  |  [NGB..) = bucket scatter.
// R8: LDS 48KB -> 32KB via W1 staged in TWO 16KB HALVES (reloaded once,
// L2-hot) -> 5 blocks/CU. launch_bounds(256,4) keeps VGPR budget at 128
// (R5 body compiled at 80) -> NO spill (R7's (256,6) spilled acc to
// scratch: VGPR 40, 188us). Scatter branch occupancy 12 -> ~20 waves/CU.
// ===========================================================================
__global__ __launch_bounds__(256, 4)
void k_fused(const int* __restrict__ srcv, const int* __restrict__ dstv,
             int* __restrict__ cursor, int* __restrict__ bucket,
             const float* __restrict__ x, const float* __restrict__ W1,
             const float* __restrict__ att_s, const float* __restrict__ att_d,
             unsigned int* __restrict__ rec, float* __restrict__ a_d) {
    __shared__ __align__(16) char smem[32768];
    int tid = threadIdx.x;
    if (blockIdx.x < NGB) {
        // ---------------- lin1: rec = x @ W1 (fp8 + a_s), attention dots ---
        float4* sW = (float4*)smem;                         // 16384 B: 64 k-rows
        float (*sxT)[256] = (float(*)[256])(smem + 16384);  // 16384 B
        const float4* W4 = (const float4*)W1;
        int node0 = blockIdx.x * 256;
        int rg = tid >> 3, cg = tid & 7;     // 32 row-groups x 8 col-groups
        float acc[8][8];
#pragma unroll
        for (int ii = 0; ii < 8; ++ii)
#pragma unroll
            for (int jj = 0; jj < 8; ++jj) acc[ii][jj] = 0.f;
        const float4* x4 = (const float4*)x;
        for (int kt = 0; kt < 8; ++kt) {     // K tiles of 16
            if (kt) __syncthreads();         // readers done with prev tile
            if ((kt & 3) == 0) {             // stage W half (64 k-rows, 16KB)
                const float4* Wh = W4 + (kt >> 2) * 1024;
#pragma unroll
                for (int q = 0; q < 4; ++q) sW[q * 256 + tid] = Wh[q * 256 + tid];
            }
#pragma unroll
            for (int q = 0; q < 4; ++q) {    // stage 256 rows x 16 k, transposed
                int i = q * 256 + tid;
                int r = i >> 2, kc = i & 3;
                int gn = node0 + r;
                float4 v = {0.f, 0.f, 0.f, 0.f};
                if (gn < NN) v = x4[(size_t)gn * 32 + kt * 4 + kc];
                int cs = r ^ (kc << 3);      // swizzle: s = (k>>2)<<3, k>>2 = kc
                sxT[kc * 4 + 0][cs] = v.x;
                sxT[kc * 4 + 1][cs] = v.y;
                sxT[kc * 4 + 2][cs] = v.z;
                sxT[kc * 4 + 3][cs] = v.w;
            }
            __syncthreads();
#pragma unroll 4
            for (int kk = 0; kk < 16; ++kk) {
                int sw = (kk >> 2) << 3;
                const float* xr = &sxT[kk][(rg * 8) ^ sw];
                float4 xa = *(const float4*)xr;
                float4 xb = *(const float4*)(xr + 4);
                int kl = (kt & 3) * 16 + kk;     // k-row within staged half
                float4 wa = sW[kl * 16 + cg * 2];
                float4 wb = sW[kl * 16 + cg * 2 + 1];
                float xv[8] = {xa.x, xa.y, xa.z, xa.w, xb.x, xb.y, xb.z, xb.w};
                float wv[8] = {wa.x, wa.y, wa.z, wa.w, wb.x, wb.y, wb.z, wb.w};
#pragma unroll
                for (int ii = 0; ii < 8; ++ii)
#pragma unroll
                    for (int jj = 0; jj < 8; ++jj)
                        acc[ii][jj] = fmaf(xv[ii], wv[jj], acc[ii][jj]);
            }
        }
        // epilogue: fp8 pack + per-head attention dots (head == cg, no reduce)
        float4 s0 = ((const float4*)att_s)[cg * 2];
        float4 s1 = ((const float4*)att_s)[cg * 2 + 1];
        float4 d0 = ((const float4*)att_d)[cg * 2];
        float4 d1 = ((const float4*)att_d)[cg * 2 + 1];
        uint2* hp2 = (uint2*)rec;
        __half* ash = (__half*)rec;
#pragma unroll
        for (int ii = 0; ii < 8; ++ii) {
            int n = node0 + rg * 8 + ii;
            if (n < NN) {
                float* a = acc[ii];
                int p0 = __builtin_amdgcn_cvt_pk_fp8_f32(a[0], a[1], 0, false);
                p0 = __builtin_amdgcn_cvt_pk_fp8_f32(a[2], a[3], p0, true);
                int p1 = __builtin_amdgcn_cvt_pk_fp8_f32(a[4], a[5], 0, false);
                p1 = __builtin_amdgcn_cvt_pk_fp8_f32(a[6], a[7], p1, true);
                uint2 pk; pk.x = (unsigned)p0; pk.y = (unsigned)p1;
                hp2[n * 16 + cg] = pk;       // record stride 128B = 16 uint2
                float as = a[0] * s0.x;
                as = fmaf(a[1], s0.y, as); as = fmaf(a[2], s0.z, as);
                as = fmaf(a[3], s0.w, as); as = fmaf(a[4], s1.x, as);
                as = fmaf(a[5], s1.y, as); as = fmaf(a[6], s1.z, as);
                as = fmaf(a[7], s1.w, as);
                float ad = a[0] * d0.x;
                ad = fmaf(a[1], d0.y, ad); ad = fmaf(a[2], d0.z, ad);
                ad = fmaf(a[3], d0.w, ad); ad = fmaf(a[4], d1.x, ad);
                ad = fmaf(a[5], d1.y, ad); ad = fmaf(a[6], d1.z, ad);
                ad = fmaf(a[7], d1.w, ad);
                ash[n * 64 + 32 + cg] = __float2half(as);   // byte 64 + 2*cg
                a_d[n * 8 + cg] = ad;
            }
        }
    } else {
        // ---------------- bucket scatter (128-node bins) ----------------
        int* hcnt  = (int*)smem;          // BINS (3128B)
        int* hbase = hcnt + BINS;         // BINS
        for (int i = tid; i < BINS; i += 256) hcnt[i] = 0;
        __syncthreads();
        int e0 = (blockIdx.x - NGB) * 2048;
        int bn[8], rk[8], pk[8];
#pragma unroll
        for (int q = 0; q < 8; ++q) {
            int e = e0 + q * 256 + tid;
            if (e < EE) {
                int s = srcv[e], d = dstv[e];
                bn[q] = d >> BSHIFT;
                pk[q] = (s << BSHIFT) | (d & BMASK);
                rk[q] = atomicAdd(&hcnt[bn[q]], 1);   // LDS atomic
            } else bn[q] = -1;
        }
        __syncthreads();
        for (int i = tid; i < BINS; i += 256) {
            int c = hcnt[i];
            hbase[i] = c ? atomicAdd(&cursor[i], c) : 0;
        }
        __syncthreads();
#pragma unroll
        for (int q = 0; q < 8; ++q) {
            if (bn[q] >= 0) {
                int p = hbase[bn[q]] + rk[q];
                if (p < BCAP) bucket[bn[q] * BCAP + p] = pk[q];
            }
        }
    }
}

// ===========================================================================
// P3: per-bin fine CSR, SINGLE-PASS: bin segment cached in LDS during the
// histogram read; scatter pass reads LDS (no second global walk of bucket).
// One block per 128-node bin.
// ===========================================================================
__global__ __launch_bounds__(256)
void k_binCSR(const int* __restrict__ cursor, const int* __restrict__ bucket,
              int* __restrict__ col, int* __restrict__ rbeg, int* __restrict__ rend) {
    __shared__ int sseg[BCAP];           // 19200 B
    __shared__ int cnt_[BNODE];
    __shared__ int tmp[BNODE];
    __shared__ int cur[BNODE];
    int b = blockIdx.x, tid = threadIdx.x;
    if (tid < BNODE) cnt_[tid] = 0;
    __syncthreads();
    int m = cursor[b]; if (m > BCAP) m = BCAP;
    const int* seg = bucket + b * BCAP;
    for (int i = tid; i < m; i += 256) {
        int v = seg[i];
        sseg[i] = v;
        atomicAdd(&cnt_[v & BMASK], 1);
    }
    __syncthreads();
    if (tid < BNODE) tmp[tid] = cnt_[tid];
    __syncthreads();
    for (int off = 1; off < BNODE; off <<= 1) {
        int t = (tid >= off && tid < BNODE) ? tmp[tid - off] : 0;
        __syncthreads();
        if (tid < BNODE) tmp[tid] += t;
        __syncthreads();
    }
    if (tid < BNODE) {
        int excl = tmp[tid] - cnt_[tid];
        int n = b * BNODE + tid;
        if (n < NN) {
            rbeg[n] = b * BCAP + excl;
            rend[n] = b * BCAP + excl + cnt_[tid];
        }
        cur[tid] = excl;
    }
    __syncthreads();
    for (int i = tid; i < m; i += 256) {
        int pkv = sseg[i];
        int r = atomicAdd(&cur[pkv & BMASK], 1);
        col[b * BCAP + r] = pkv >> BSHIFT;
    }
}

// ===========================================================================
// Agg layer 1 (8 heads). Wave = 2 nodes x (4 edge-slots x 8 lanes), lane&7 =
// head = ch-group (uint2 fp8 row slice). 1-deep index prefetch (pad-safe).
// a_src read from the SAME 128B record line as the h gather.
// ===========================================================================
__global__ __launch_bounds__(256, 8)
void k_gat_agg1(const int* __restrict__ rbeg, const int* __restrict__ rend,
                const int* __restrict__ col,
                const unsigned int* __restrict__ rec, const float* __restrict__ a_d,
                const float* __restrict__ b1, float* __restrict__ out) {
    int wv = threadIdx.x >> 6;
    int lane = threadIdx.x & 63;
    int half = lane >> 5;
    int d = blockIdx.x * 8 + wv * 2 + half;
    int gs = (lane >> 3) & 3;   // slot within node
    int l = lane & 7;           // head / ch-group
    int rb = rbeg[d], re = rend[d];
    float adh = a_d[d * 8 + l];
    const uint2* hp = (const uint2*)rec;
    const __half* asr = (const __half*)rec;
    uint2 rself = hp[d * 16 + l];
    float asself = __half2float(asr[d * 64 + 32 + l]);
    float ac[8] = {0.f,0.f,0.f,0.f,0.f,0.f,0.f,0.f};
    float denom = 0.f;
    int e = rb + gs;
    int s[4];
#pragma unroll
    for (int q = 0; q < 4; ++q) s[q] = col[e + 4 * q];   // pad-safe preload
    for (; e + 12 < re; ) {
        uint2 rr[4]; float asv[4]; int sn[4];
#pragma unroll
        for (int q = 0; q < 4; ++q) rr[q] = hp[(unsigned)(s[q] * 16 + l)];
#pragma unroll
        for (int q = 0; q < 4; ++q) asv[q] = __half2float(asr[(unsigned)(s[q] * 64 + 32 + l)]);
        int en = e + 16;
#pragma unroll
        for (int q = 0; q < 4; ++q) sn[q] = col[en + 4 * q];  // prefetch next
#pragma unroll
        for (int q = 0; q < 4; ++q) {
            float xx = asv[q] + adh;
            xx = xx >= 0.f ? xx : NEG * xx;
            float w = __expf(xx);
            denom += w;
            v2f f0 = __builtin_amdgcn_cvt_pk_f32_fp8((int)rr[q].x, false);
            v2f f1 = __builtin_amdgcn_cvt_pk_f32_fp8((int)rr[q].x, true);
            v2f f2 = __builtin_amdgcn_cvt_pk_f32_fp8((int)rr[q].y, false);
            v2f f3 = __builtin_amdgcn_cvt_pk_f32_fp8((int)rr[q].y, true);
            ac[0] = fmaf(f0.x, w, ac[0]); ac[1] = fmaf(f0.y, w, ac[1]);
            ac[2] = fmaf(f1.x, w, ac[2]); ac[3] = fmaf(f1.y, w, ac[3]);
            ac[4] = fmaf(f2.x, w, ac[4]); ac[5] = fmaf(f2.y, w, ac[5]);
            ac[6] = fmaf(f3.x, w, ac[6]); ac[7] = fmaf(f3.y, w, ac[7]);
        }
        e = en;
#pragma unroll
        for (int q = 0; q < 4; ++q) s[q] = sn[q];
    }
    for (; e < re; e += 4) {
        int s0 = col[e];
        uint2 r0 = hp[(unsigned)(s0 * 16 + l)];
        float x0 = __half2float(asr[(unsigned)(s0 * 64 + 32 + l)]) + adh;
        x0 = x0 >= 0.f ? x0 : NEG * x0;
        float w0 = __expf(x0);
        denom += w0;
        v2f f0 = __builtin_amdgcn_cvt_pk_f32_fp8((int)r0.x, false);
        v2f f1 = __builtin_amdgcn_cvt_pk_f32_fp8((int)r0.x, true);
        v2f f2 = __builtin_amdgcn_cvt_pk_f32_fp8((int)r0.y, false);
        v2f f3 = __builtin_amdgcn_cvt_pk_f32_fp8((int)r0.y, true);
        ac[0] = fmaf(f0.x, w0, ac[0]); ac[1] = fmaf(f0.y, w0, ac[1]);
        ac[2] = fmaf(f1.x, w0, ac[2]); ac[3] = fmaf(f1.y, w0, ac[3]);
        ac[4] = fmaf(f2.x, w0, ac[4]); ac[5] = fmaf(f2.y, w0, ac[5]);
        ac[6] = fmaf(f3.x, w0, ac[6]); ac[7] = fmaf(f3.y, w0, ac[7]);
    }
    if (gs == 0) {      // self-loop contribution
        float es = asself + adh;
        es = es >= 0.f ? es : NEG * es;
        float w = __expf(es);
        denom += w;
        v2f f0 = __builtin_amdgcn_cvt_pk_f32_fp8((int)rself.x, false);
        v2f f1 = __builtin_amdgcn_cvt_pk_f32_fp8((int)rself.x, true);
        v2f f2 = __builtin_amdgcn_cvt_pk_f32_fp8((int)rself.y, false);
        v2f f3 = __builtin_amdgcn_cvt_pk_f32_fp8((int)rself.y, true);
        ac[0] = fmaf(f0.x, w, ac[0]); ac[1] = fmaf(f0.y, w, ac[1]);
        ac[2] = fmaf(f1.x, w, ac[2]); ac[3] = fmaf(f1.y, w, ac[3]);
        ac[4] = fmaf(f2.x, w, ac[4]); ac[5] = fmaf(f2.y, w, ac[5]);
        ac[6] = fmaf(f3.x, w, ac[6]); ac[7] = fmaf(f3.y, w, ac[7]);
    }
#pragma unroll
    for (int i = 0; i < 8; ++i) {     // reduce 4 slots (stays within 32-half)
        ac[i] += __shfl_xor(ac[i], 8, 64);
        ac[i] += __shfl_xor(ac[i], 16, 64);
    }
    denom += __shfl_xor(denom, 8, 64);
    denom += __shfl_xor(denom, 16, 64);
    if (gs == 0) {
        float inv = 1.0f / denom;
        float4 b0 = ((const float4*)b1)[l * 2];
        float4 b4 = ((const float4*)b1)[l * 2 + 1];
        float4 r0, r1;
        r0.x = fmaf(ac[0], inv, b0.x); r0.x = r0.x > 0.f ? r0.x : expm1f(r0.x);
        r0.y = fmaf(ac[1], inv, b0.y); r0.y = r0.y > 0.f ? r0.y : expm1f(r0.y);
        r0.z = fmaf(ac[2], inv, b0.z); r0.z = r0.z > 0.f ? r0.z : expm1f(r0.z);
        r0.w = fmaf(ac[3], inv, b0.w); r0.w = r0.w > 0.f ? r0.w : expm1f(r0.w);
        r1.x = fmaf(ac[4], inv, b4.x); r1.x = r1.x > 0.f ? r1.x : expm1f(r1.x);
        r1.y = fmaf(ac[5], inv, b4.y); r1.y = r1.y > 0.f ? r1.y : expm1f(r1.y);
        r1.z = fmaf(ac[6], inv, b4.z); r1.z = r1.z > 0.f ? r1.z : expm1f(r1.z);
        r1.w = fmaf(ac[7], inv, b4.w); r1.w = r1.w > 0.f ? r1.w : expm1f(r1.w);
        ((float4*)out)[d * 16 + l * 2]     = r0;
        ((float4*)out)[d * 16 + l * 2 + 1] = r1;
    }
}

// ===========================================================================
// K5: rec = hin @ W2 (fp8 + a_s2 in 128B records) + a_d2. Register-tiled
// 8x8: 256 nodes/block, K=64 in 2 tiles of 32, LDS 48KB. Overwrites the
// layer-1 records (agg1 already complete; stream-ordered).
// ===========================================================================
__global__ __launch_bounds__(256, 3)
void k_lin2(const float* __restrict__ hin, const float* __restrict__ W2,
            const float* __restrict__ att_s, const float* __restrict__ att_d,
            unsigned int* __restrict__ rec, float* __restrict__ a_d) {
    __shared__ float4 sW4[D1 * 16];      // 16 KB
    __shared__ float sxT[32][256];       // 32 KB
    int tid = threadIdx.x;
    const float4* W4 = (const float4*)W2;
    for (int i = tid; i < D1 * 16; i += 256) sW4[i] = W4[i];
    int node0 = blockIdx.x * 256;
    int rg = tid >> 3, cg = tid & 7;
    float acc[8][8];
#pragma unroll
    for (int ii = 0; ii < 8; ++ii)
#pragma unroll
        for (int jj = 0; jj < 8; ++jj) acc[ii][jj] = 0.f;
    const float4* x4 = (const float4*)hin;
    for (int kt = 0; kt < 2; ++kt) {     // K tiles of 32
        if (kt) __syncthreads();
#pragma unroll
        for (int q = 0; q < 8; ++q) {    // stage 256 rows x 32 k, transposed
            int i = q * 256 + tid;
            int r = i >> 3, kc = i & 7;
            int gn = node0 + r;
            float4 v = {0.f, 0.f, 0.f, 0.f};
            if (gn < NN) v = x4[(size_t)gn * 16 + kt * 8 + kc];
            int cs = r ^ (kc << 3);
            sxT[kc * 4 + 0][cs] = v.x;
            sxT[kc * 4 + 1][cs] = v.y;
            sxT[kc * 4 + 2][cs] = v.z;
            sxT[kc * 4 + 3][cs] = v.w;
        }
        __syncthreads();
#pragma unroll 4
        for (int kk = 0; kk < 32; ++kk) {
            int sw = (kk >> 2) << 3;
            const float* xr = &sxT[kk][(rg * 8) ^ sw];
            float4 xa = *(const float4*)xr;
            float4 xb = *(const float4*)(xr + 4);
            int kg = kt * 32 + kk;
            float4 wa = sW4[kg * 16 + cg * 2];
            float4 wb = sW4[kg * 16 + cg * 2 + 1];
            float xv[8] = {xa.x, xa.y, xa.z, xa.w, xb.x, xb.y, xb.z, xb.w};
            float wv[8] = {wa.x, wa.y, wa.z, wa.w, wb.x, wb.y, wb.z, wb.w};
#pragma unroll
            for (int ii = 0; ii < 8; ++ii)
#pragma unroll
                for (int jj = 0; jj < 8; ++jj)
                    acc[ii][jj] = fmaf(xv[ii], wv[jj], acc[ii][jj]);
        }
    }
    // epilogue: fp8 pack + single-head dots (reduce over 8 cg lanes)
    float4 s0 = ((const float4*)att_s)[cg * 2];
    float4 s1 = ((const float4*)att_s)[cg * 2 + 1];
    float4 d0 = ((const float4*)att_d)[cg * 2];
    float4 d1 = ((const float4*)att_d)[cg * 2 + 1];
    uint2* hp2 = (uint2*)rec;
#pragma unroll
    for (int ii = 0; ii < 8; ++ii) {
        int n = node0 + rg * 8 + ii;
        if (n < NN) {
            float* a = acc[ii];
            int p0 = __builtin_amdgcn_cvt_pk_fp8_f32(a[0], a[1], 0, false);
            p0 = __builtin_amdgcn_cvt_pk_fp8_f32(a[2], a[3], p0, true);
            int p1 = __builtin_amdgcn_cvt_pk_fp8_f32(a[4], a[5], 0, false);
            p1 = __builtin_amdgcn_cvt_pk_fp8_f32(a[6], a[7], p1, true);
            uint2 pk; pk.x = (unsigned)p0; pk.y = (unsigned)p1;
            hp2[n * 16 + cg] = pk;
            float vs = a[0] * s0.x;
            vs = fmaf(a[1], s0.y, vs); vs = fmaf(a[2], s0.z, vs);
            vs = fmaf(a[3], s0.w, vs); vs = fmaf(a[4], s1.x, vs);
            vs = fmaf(a[5], s1.y, vs); vs = fmaf(a[6], s1.z, vs);
            vs = fmaf(a[7], s1.w, vs);
            float vd = a[0] * d0.x;
            vd = fmaf(a[1], d0.y, vd); vd = fmaf(a[2], d0.z, vd);
            vd = fmaf(a[3], d0.w, vd); vd = fmaf(a[4], d1.x, vd);
            vd = fmaf(a[5], d1.y, vd); vd = fmaf(a[6], d1.z, vd);
            vd = fmaf(a[7], d1.w, vd);
            vs += __shfl_xor(vs, 1, 64); vs += __shfl_xor(vs, 2, 64);
            vs += __shfl_xor(vs, 4, 64);
            vd += __shfl_xor(vd, 1, 64); vd += __shfl_xor(vd, 2, 64);
            vd += __shfl_xor(vd, 4, 64);
            if (cg == 0) {
                ((float*)rec)[(size_t)n * 32 + 16] = vs;   // byte offset 64
                a_d[n] = vd;
            }
        }
    }
}

// ===========================================================================
// Agg layer 2 (1 head). Same 2-node/wave pipelined structure; a_s2 read
// from the same 128B record line as the h gather. Fused bias + mean-pool.
// ===========================================================================
__global__ __launch_bounds__(256, 8)
void k_gat_agg2(const int* __restrict__ rbeg, const int* __restrict__ rend,
                const int* __restrict__ col,
                const unsigned int* __restrict__ rec, const float* __restrict__ a_d,
                const float* __restrict__ b2, const int* __restrict__ batch,
                float* __restrict__ pool, float* __restrict__ cnt) {
    __shared__ float sv[8][64];
    __shared__ int sgi[8];
    int wv = threadIdx.x >> 6;
    int lane = threadIdx.x & 63;
    int half = lane >> 5;
    int idx = wv * 2 + half;
    int d = blockIdx.x * 8 + idx;
    int gs = (lane >> 3) & 3;
    int l = lane & 7;
    int rb = rbeg[d], re = rend[d];
    float ad = a_d[d];
    const uint2* hp = (const uint2*)rec;
    const float* recf = (const float*)rec;
    uint2 rself = hp[d * 16 + l];
    float asself = recf[d * 32 + 16];
    if (gs == 0 && l == 0) sgi[idx] = batch[d];
    float ac[8] = {0.f,0.f,0.f,0.f,0.f,0.f,0.f,0.f};
    float denom = 0.f;
    int e = rb + gs;
    int s[4];
#pragma unroll
    for (int q = 0; q < 4; ++q) s[q] = col[e + 4 * q];
    for (; e + 12 < re; ) {
        uint2 rr[4]; float asv[4]; int sn[4];
#pragma unroll
        for (int q = 0; q < 4; ++q) rr[q] = hp[(unsigned)(s[q] * 16 + l)];
#pragma unroll
        for (int q = 0; q < 4; ++q) asv[q] = recf[(unsigned)(s[q] * 32 + 16)];
        int en = e + 16;
#pragma unroll
        for (int q = 0; q < 4; ++q) sn[q] = col[en + 4 * q];
#pragma unroll
        for (int q = 0; q < 4; ++q) {
            float xx = asv[q] + ad;
            xx = xx >= 0.f ? xx : NEG * xx;
            float w = __expf(xx);
            denom += w;
            v2f f0 = __builtin_amdgcn_cvt_pk_f32_fp8((int)rr[q].x, false);
            v2f f1 = __builtin_amdgcn_cvt_pk_f32_fp8((int)rr[q].x, true);
            v2f f2 = __builtin_amdgcn_cvt_pk_f32_fp8((int)rr[q].y, false);
            v2f f3 = __builtin_amdgcn_cvt_pk_f32_fp8((int)rr[q].y, true);
            ac[0] = fmaf(f0.x, w, ac[0]); ac[1] = fmaf(f0.y, w, ac[1]);
            ac[2] = fmaf(f1.x, w, ac[2]); ac[3] = fmaf(f1.y, w, ac[3]);
            ac[4] = fmaf(f2.x, w, ac[4]); ac[5] = fmaf(f2.y, w, ac[5]);
            ac[6] = fmaf(f3.x, w, ac[6]); ac[7] = fmaf(f3.y, w, ac[7]);
        }
        e = en;
#pragma unroll
        for (int q = 0; q < 4; ++q) s[q] = sn[q];
    }
    for (; e < re; e += 4) {
        int s0 = col[e];
        uint2 r0 = hp[(unsigned)(s0 * 16 + l)];
        float x0 = recf[(unsigned)(s0 * 32 + 16)] + ad;
        x0 = x0 >= 0.f ? x0 : NEG * x0;
        float w0 = __expf(x0);
        denom += w0;
        v2f f0 = __builtin_amdgcn_cvt_pk_f32_fp8((int)r0.x, false);
        v2f f1 = __builtin_amdgcn_cvt_pk_f32_fp8((int)r0.x, true);
        v2f f2 = __builtin_amdgcn_cvt_pk_f32_fp8((int)r0.y, false);
        v2f f3 = __builtin_amdgcn_cvt_pk_f32_fp8((int)r0.y, true);
        ac[0] = fmaf(f0.x, w0, ac[0]); ac[1] = fmaf(f0.y, w0, ac[1]);
        ac[2] = fmaf(f1.x, w0, ac[2]); ac[3] = fmaf(f1.y, w0, ac[3]);
        ac[4] = fmaf(f2.x, w0, ac[4]); ac[5] = fmaf(f2.y, w0, ac[5]);
        ac[6] = fmaf(f3.x, w0, ac[6]); ac[7] = fmaf(f3.y, w0, ac[7]);
    }
    if (gs == 0) {
        float es = asself + ad;
        es = es >= 0.f ? es : NEG * es;
        float w = __expf(es);
        denom += w;
        v2f f0 = __builtin_amdgcn_cvt_pk_f32_fp8((int)rself.x, false);
        v2f f1 = __builtin_amdgcn_cvt_pk_f32_fp8((int)rself.x, true);
        v2f f2 = __builtin_amdgcn_cvt_pk_f32_fp8((int)rself.y, false);
        v2f f3 = __builtin_amdgcn_cvt_pk_f32_fp8((int)rself.y, true);
        ac[0] = fmaf(f0.x, w, ac[0]); ac[1] = fmaf(f0.y, w, ac[1]);
        ac[2] = fmaf(f1.x, w, ac[2]); ac[3] = fmaf(f1.y, w, ac[3]);
        ac[4] = fmaf(f2.x, w, ac[4]); ac[5] = fmaf(f2.y, w, ac[5]);
        ac[6] = fmaf(f3.x, w, ac[6]); ac[7] = fmaf(f3.y, w, ac[7]);
    }
#pragma unroll
    for (int i = 0; i < 8; ++i) {
        ac[i] += __shfl_xor(ac[i], 8, 64);
        ac[i] += __shfl_xor(ac[i], 16, 64);
    }
    denom += __shfl_xor(denom, 8, 64);
    denom += __shfl_xor(denom, 16, 64);
    if (gs == 0) {
        float inv = 1.0f / denom;
#pragma unroll
        for (int i = 0; i < 8; ++i)
            sv[idx][l * 8 + i] = fmaf(ac[i], inv, b2[l * 8 + i]);
    }
    __syncthreads();
    int tid = threadIdx.x;
    if (tid < 64) {
        float acc = sv[0][tid]; int curg = sgi[0];
        for (int r = 1; r < 8; ++r) {
            if (sgi[r] == curg) acc += sv[r][tid];
            else { atomicAdd(&pool[curg * 64 + tid], acc); curg = sgi[r]; acc = sv[r][tid]; }
        }
        atomicAdd(&pool[curg * 64 + tid], acc);
    } else if (tid == 64) {
        float c = 1.f; int curg = sgi[0];
        for (int r = 1; r < 8; ++r) {
            if (sgi[r] == curg) c += 1.f;
            else { atomicAdd(&cnt[curg], c); curg = sgi[r]; c = 1.f; }
        }
        atomicAdd(&cnt[curg], c);
    }
}

// K9: g = pool/cnt ; hidden = elu(g@lw1+lb1) ; out = hidden@lw2 + lb2
__global__ __launch_bounds__(128)
void k_mlp(const float* __restrict__ pool, const float* __restrict__ cnt,
           const float* __restrict__ lw1, const float* __restrict__ lb1,
           const float* __restrict__ lw2, const float* __restrict__ lb2,
           float* __restrict__ out) {
    __shared__ float sg[OUTC];
    __shared__ float sh[HID];
    int g = blockIdx.x, tid = threadIdx.x;
    float c = fmaxf(cnt[g], 1.0f);
    if (tid < OUTC) sg[tid] = pool[g * OUTC + tid] / c;
    __syncthreads();
    float acc = lb1[tid];
#pragma unroll 8
    for (int k = 0; k < OUTC; ++k)
        acc = fmaf(sg[k], lw1[k * HID + tid], acc);
    acc = acc > 0.f ? acc : expm1f(acc);
    sh[tid] = acc * lw2[tid];
    __syncthreads();
    for (int off = 64; off >= 1; off >>= 1) {
        if (tid < off) sh[tid] += sh[tid + off];
        __syncthreads();
    }
    if (tid == 0) out[g] = sh[0] + lb2[0];
}

extern "C" void kernel_launch(void* const* d_in, const int* in_sizes, int n_in,
                              void* d_out, int out_size, void* d_ws, size_t ws_size,
                              hipStream_t stream) {
    const float* x    = (const float*)d_in[0];
    const int*   ei   = (const int*)d_in[1];
    const int*   batch= (const int*)d_in[2];
    const float* W1   = (const float*)d_in[3];
    const float* as1  = (const float*)d_in[4];
    const float* ad1  = (const float*)d_in[5];
    const float* b1   = (const float*)d_in[6];
    const float* W2   = (const float*)d_in[7];
    const float* as2  = (const float*)d_in[8];
    const float* ad2  = (const float*)d_in[9];
    const float* b2   = (const float*)d_in[10];
    const float* lw1  = (const float*)d_in[11];
    const float* lb1  = (const float*)d_in[12];
    const float* lw2  = (const float*)d_in[13];
    const float* lb2  = (const float*)d_in[14];
    float* out = (float*)d_out;

    // workspace layout (~73 MB); colv has +1024-int pad for pipelined preloads
    unsigned int* REC = (unsigned int*)d_ws;         // N*32 uints = 128B records (12.8 MB)
    float* B    = (float*)(REC + (size_t)NN * 32);   // N*64 fp32 (25.6 MB)
    float* aD1  = B + (size_t)NN * 64;               // N*8
    float* aD2  = aD1 + (size_t)NN * 8;              // N
    float* pool = aD2 + NN;                          // G*64
    float* cntp = pool + GG * 64;                    // G
    int* rbeg   = (int*)(cntp + GG);                 // N
    int* rend   = rbeg + NN;                         // N
    int* cursor = rend + NN;                         // BINS
    int* bucket = cursor + BINS;                     // BINS*BCAP (15.0 MB)
    int* colv   = bucket + (size_t)BINS * BCAP;      // BINS*BCAP + pad

    const int* srcv = ei;
    const int* dstv = ei + EE;

    hipMemsetAsync(cursor, 0, BINS * sizeof(int), stream);
    hipMemsetAsync(pool, 0, (size_t)(GG * 64 + GG) * sizeof(float), stream);

    // FUSED: lin1 GEMM (391 long blocks, first) + bucket scatter (1563 short)
    k_fused<<<NGB + BKBLK, 256, 0, stream>>>(srcv, dstv, cursor, bucket,
                                             x, W1, as1, ad1, REC, aD1);
    k_binCSR<<<BINS, 256, 0, stream>>>(cursor, bucket, colv, rbeg, rend);

    // layer 1 aggregation
    k_gat_agg1<<<NN / 8, 256, 0, stream>>>(rbeg, rend, colv, REC, aD1, b1, B);

    // layer 2 (lin2 overwrites REC with layer-2 records; stream-ordered)
    k_lin2    <<<NGB, 256, 0, stream>>>(B, W2, as2, ad2, REC, aD2);
    k_gat_agg2<<<NN / 8, 256, 0, stream>>>(rbeg, rend, colv, REC, aD2, b2, batch, pool, cntp);

    // MLP head
    k_mlp<<<GG, 128, 0, stream>>>(pool, cntp, lw1, lb1, lw2, lb2, out);
}

// Round 10
// 352.109 us; speedup vs baseline: 1.9524x; 1.0474x over previous
//
#include <hip/hip_runtime.h>
#include <hip/hip_fp16.h>
#include <math.h>

// Problem constants (match reference)
#define NN   100000
#define EE   3200000
#define GG   512
#define INC  128
#define D1   64        // H1*C1 = 8*8
#define OUTC 64
#define HID  128
#define NEG  0.2f

// Two-level CSR binning: 128-node bins
#define BINS   782     // ceil(NN/128)
#define BNODE  128
#define BSHIFT 7
#define BMASK  127
#define BCAP   4800    // Binomial mean 4096 + 11 sigma; overflow-guarded
#define BKBLK 1563     // ceil(EE/2048) bucket blocks in the fused kernel
#define NGB 391        // ceil(NN/256) register-tiled GEMM blocks

typedef __attribute__((ext_vector_type(2))) float v2f;

// Node record layout (both layers, shared buffer REC, 128B/node aligned):
//   bytes  0..63 : 64 x fp8 h-row
//   bytes 64..79 : layer1: 8 x half a_src   | layer2: float a_src at byte 64
//   bytes 80..127: pad
// One 128B line per edge-gather: the a_src read lands in the SAME line as
// the h gather -> second L1 request per edge becomes a line hit.

// ===========================================================================
// FUSED: [blocks 0..NGB) = lin1 GEMM  |  [NGB..) = bucket scatter.
// EXACT R5 form (350.8us proven): 48KB LDS resident W1, launch_bounds(256,3)
// -> VGPR 80, no spill. R7 ((256,6): spill, 188us) and R8 ((256,4)+W-halves:
// 88us + cold-start) both showed occupancy pushes here are net losses.
// ===========================================================================
__global__ __launch_bounds__(256, 3)
void k_fused(const int* __restrict__ srcv, const int* __restrict__ dstv,
             int* __restrict__ cursor, int* __restrict__ bucket,
             const float* __restrict__ x, const float* __restrict__ W1,
             const float* __restrict__ att_s, const float* __restrict__ att_d,
             unsigned int* __restrict__ rec, float* __restrict__ a_d) {
    __shared__ __align__(16) char smem[49152];
    int tid = threadIdx.x;
    if (blockIdx.x < NGB) {
        // ---------------- lin1: rec = x @ W1 (fp8 + a_s), attention dots ---
        float4* sW4 = (float4*)smem;                        // 32768 B
        float (*sxT)[256] = (float(*)[256])(smem + 32768);  // 16x256x4 = 16384 B
        const float4* W4 = (const float4*)W1;
        for (int i = tid; i < 128 * 16; i += 256) sW4[i] = W4[i];
        int node0 = blockIdx.x * 256;
        int rg = tid >> 3, cg = tid & 7;     // 32 row-groups x 8 col-groups
        float acc[8][8];
#pragma unroll
        for (int ii = 0; ii < 8; ++ii)
#pragma unroll
            for (int jj = 0; jj < 8; ++jj) acc[ii][jj] = 0.f;
        const float4* x4 = (const float4*)x;
        for (int kt = 0; kt < 8; ++kt) {     // K tiles of 16
            if (kt) __syncthreads();         // readers done with prev tile
#pragma unroll
            for (int q = 0; q < 4; ++q) {    // stage 256 rows x 16 k, transposed
                int i = q * 256 + tid;
                int r = i >> 2, kc = i & 3;
                int gn = node0 + r;
                float4 v = {0.f, 0.f, 0.f, 0.f};
                if (gn < NN) v = x4[(size_t)gn * 32 + kt * 4 + kc];
                int cs = r ^ (kc << 3);      // swizzle: s = (k>>2)<<3, k>>2 = kc
                sxT[kc * 4 + 0][cs] = v.x;
                sxT[kc * 4 + 1][cs] = v.y;
                sxT[kc * 4 + 2][cs] = v.z;
                sxT[kc * 4 + 3][cs] = v.w;
            }
            __syncthreads();
#pragma unroll 4
            for (int kk = 0; kk < 16; ++kk) {
                int sw = (kk >> 2) << 3;
                const float* xr = &sxT[kk][(rg * 8) ^ sw];
                float4 xa = *(const float4*)xr;
                float4 xb = *(const float4*)(xr + 4);
                int kg = kt * 16 + kk;
                float4 wa = sW4[kg * 16 + cg * 2];
                float4 wb = sW4[kg * 16 + cg * 2 + 1];
                float xv[8] = {xa.x, xa.y, xa.z, xa.w, xb.x, xb.y, xb.z, xb.w};
                float wv[8] = {wa.x, wa.y, wa.z, wa.w, wb.x, wb.y, wb.z, wb.w};
#pragma unroll
                for (int ii = 0; ii < 8; ++ii)
#pragma unroll
                    for (int jj = 0; jj < 8; ++jj)
                        acc[ii][jj] = fmaf(xv[ii], wv[jj], acc[ii][jj]);
            }
        }
        // epilogue: fp8 pack + per-head attention dots (head == cg, no reduce)
        float4 s0 = ((const float4*)att_s)[cg * 2];
        float4 s1 = ((const float4*)att_s)[cg * 2 + 1];
        float4 d0 = ((const float4*)att_d)[cg * 2];
        float4 d1 = ((const float4*)att_d)[cg * 2 + 1];
        uint2* hp2 = (uint2*)rec;
        __half* ash = (__half*)rec;
#pragma unroll
        for (int ii = 0; ii < 8; ++ii) {
            int n = node0 + rg * 8 + ii;
            if (n < NN) {
                float* a = acc[ii];
                int p0 = __builtin_amdgcn_cvt_pk_fp8_f32(a[0], a[1], 0, false);
                p0 = __builtin_amdgcn_cvt_pk_fp8_f32(a[2], a[3], p0, true);
                int p1 = __builtin_amdgcn_cvt_pk_fp8_f32(a[4], a[5], 0, false);
                p1 = __builtin_amdgcn_cvt_pk_fp8_f32(a[6], a[7], p1, true);
                uint2 pk; pk.x = (unsigned)p0; pk.y = (unsigned)p1;
                hp2[n * 16 + cg] = pk;       // record stride 128B = 16 uint2
                float as = a[0] * s0.x;
                as = fmaf(a[1], s0.y, as); as = fmaf(a[2], s0.z, as);
                as = fmaf(a[3], s0.w, as); as = fmaf(a[4], s1.x, as);
                as = fmaf(a[5], s1.y, as); as = fmaf(a[6], s1.z, as);
                as = fmaf(a[7], s1.w, as);
                float ad = a[0] * d0.x;
                ad = fmaf(a[1], d0.y, ad); ad = fmaf(a[2], d0.z, ad);
                ad = fmaf(a[3], d0.w, ad); ad = fmaf(a[4], d1.x, ad);
                ad = fmaf(a[5], d1.y, ad); ad = fmaf(a[6], d1.z, ad);
                ad = fmaf(a[7], d1.w, ad);
                ash[n * 64 + 32 + cg] = __float2half(as);   // byte 64 + 2*cg
                a_d[n * 8 + cg] = ad;
            }
        }
    } else {
        // ---------------- bucket scatter (128-node bins) ----------------
        int* hcnt  = (int*)smem;          // BINS (3128B)
        int* hbase = hcnt + BINS;         // BINS
        for (int i = tid; i < BINS; i += 256) hcnt[i] = 0;
        __syncthreads();
        int e0 = (blockIdx.x - NGB) * 2048;
        int bn[8], rk[8], pk[8];
#pragma unroll
        for (int q = 0; q < 8; ++q) {
            int e = e0 + q * 256 + tid;
            if (e < EE) {
                int s = srcv[e], d = dstv[e];
                bn[q] = d >> BSHIFT;
                pk[q] = (s << BSHIFT) | (d & BMASK);
                rk[q] = atomicAdd(&hcnt[bn[q]], 1);   // LDS atomic
            } else bn[q] = -1;
        }
        __syncthreads();
        for (int i = tid; i < BINS; i += 256) {
            int c = hcnt[i];
            hbase[i] = c ? atomicAdd(&cursor[i], c) : 0;
        }
        __syncthreads();
#pragma unroll
        for (int q = 0; q < 8; ++q) {
            if (bn[q] >= 0) {
                int p = hbase[bn[q]] + rk[q];
                if (p < BCAP) bucket[bn[q] * BCAP + p] = pk[q];
            }
        }
    }
}

// ===========================================================================
// P3: per-bin fine CSR, SINGLE-PASS: bin segment cached in LDS during the
// histogram read; scatter pass reads LDS (no second global walk of bucket).
// One block per 128-node bin. (Kept from R7/R8 — isolated as ~neutral-to-
// positive; saves a 15MB global re-read vs the two-pass R5 version.)
// ===========================================================================
__global__ __launch_bounds__(256)
void k_binCSR(const int* __restrict__ cursor, const int* __restrict__ bucket,
              int* __restrict__ col, int* __restrict__ rbeg, int* __restrict__ rend) {
    __shared__ int sseg[BCAP];           // 19200 B
    __shared__ int cnt_[BNODE];
    __shared__ int tmp[BNODE];
    __shared__ int cur[BNODE];
    int b = blockIdx.x, tid = threadIdx.x;
    if (tid < BNODE) cnt_[tid] = 0;
    __syncthreads();
    int m = cursor[b]; if (m > BCAP) m = BCAP;
    const int* seg = bucket + b * BCAP;
    for (int i = tid; i < m; i += 256) {
        int v = seg[i];
        sseg[i] = v;
        atomicAdd(&cnt_[v & BMASK], 1);
    }
    __syncthreads();
    if (tid < BNODE) tmp[tid] = cnt_[tid];
    __syncthreads();
    for (int off = 1; off < BNODE; off <<= 1) {
        int t = (tid >= off && tid < BNODE) ? tmp[tid - off] : 0;
        __syncthreads();
        if (tid < BNODE) tmp[tid] += t;
        __syncthreads();
    }
    if (tid < BNODE) {
        int excl = tmp[tid] - cnt_[tid];
        int n = b * BNODE + tid;
        if (n < NN) {
            rbeg[n] = b * BCAP + excl;
            rend[n] = b * BCAP + excl + cnt_[tid];
        }
        cur[tid] = excl;
    }
    __syncthreads();
    for (int i = tid; i < m; i += 256) {
        int pkv = sseg[i];
        int r = atomicAdd(&cur[pkv & BMASK], 1);
        col[b * BCAP + r] = pkv >> BSHIFT;
    }
}

// ===========================================================================
// Agg layer 1 (8 heads). Wave = 2 nodes x (4 edge-slots x 8 lanes), lane&7 =
// head = ch-group (uint2 fp8 row slice). 1-deep index prefetch (pad-safe).
// a_src read from the SAME 128B record line as the h gather.
// ===========================================================================
__global__ __launch_bounds__(256, 8)
void k_gat_agg1(const int* __restrict__ rbeg, const int* __restrict__ rend,
                const int* __restrict__ col,
                const unsigned int* __restrict__ rec, const float* __restrict__ a_d,
                const float* __restrict__ b1, float* __restrict__ out) {
    int wv = threadIdx.x >> 6;
    int lane = threadIdx.x & 63;
    int half = lane >> 5;
    int d = blockIdx.x * 8 + wv * 2 + half;
    int gs = (lane >> 3) & 3;   // slot within node
    int l = lane & 7;           // head / ch-group
    int rb = rbeg[d], re = rend[d];
    float adh = a_d[d * 8 + l];
    const uint2* hp = (const uint2*)rec;
    const __half* asr = (const __half*)rec;
    uint2 rself = hp[d * 16 + l];
    float asself = __half2float(asr[d * 64 + 32 + l]);
    float ac[8] = {0.f,0.f,0.f,0.f,0.f,0.f,0.f,0.f};
    float denom = 0.f;
    int e = rb + gs;
    int s[4];
#pragma unroll
    for (int q = 0; q < 4; ++q) s[q] = col[e + 4 * q];   // pad-safe preload
    for (; e + 12 < re; ) {
        uint2 rr[4]; float asv[4]; int sn[4];
#pragma unroll
        for (int q = 0; q < 4; ++q) rr[q] = hp[(unsigned)(s[q] * 16 + l)];
#pragma unroll
        for (int q = 0; q < 4; ++q) asv[q] = __half2float(asr[(unsigned)(s[q] * 64 + 32 + l)]);
        int en = e + 16;
#pragma unroll
        for (int q = 0; q < 4; ++q) sn[q] = col[en + 4 * q];  // prefetch next
#pragma unroll
        for (int q = 0; q < 4; ++q) {
            float xx = asv[q] + adh;
            xx = xx >= 0.f ? xx : NEG * xx;
            float w = __expf(xx);
            denom += w;
            v2f f0 = __builtin_amdgcn_cvt_pk_f32_fp8((int)rr[q].x, false);
            v2f f1 = __builtin_amdgcn_cvt_pk_f32_fp8((int)rr[q].x, true);
            v2f f2 = __builtin_amdgcn_cvt_pk_f32_fp8((int)rr[q].y, false);
            v2f f3 = __builtin_amdgcn_cvt_pk_f32_fp8((int)rr[q].y, true);
            ac[0] = fmaf(f0.x, w, ac[0]); ac[1] = fmaf(f0.y, w, ac[1]);
            ac[2] = fmaf(f1.x, w, ac[2]); ac[3] = fmaf(f1.y, w, ac[3]);
            ac[4] = fmaf(f2.x, w, ac[4]); ac[5] = fmaf(f2.y, w, ac[5]);
            ac[6] = fmaf(f3.x, w, ac[6]); ac[7] = fmaf(f3.y, w, ac[7]);
        }
        e = en;
#pragma unroll
        for (int q = 0; q < 4; ++q) s[q] = sn[q];
    }
    for (; e < re; e += 4) {
        int s0 = col[e];
        uint2 r0 = hp[(unsigned)(s0 * 16 + l)];
        float x0 = __half2float(asr[(unsigned)(s0 * 64 + 32 + l)]) + adh;
        x0 = x0 >= 0.f ? x0 : NEG * x0;
        float w0 = __expf(x0);
        denom += w0;
        v2f f0 = __builtin_amdgcn_cvt_pk_f32_fp8((int)r0.x, false);
        v2f f1 = __builtin_amdgcn_cvt_pk_f32_fp8((int)r0.x, true);
        v2f f2 = __builtin_amdgcn_cvt_pk_f32_fp8((int)r0.y, false);
        v2f f3 = __builtin_amdgcn_cvt_pk_f32_fp8((int)r0.y, true);
        ac[0] = fmaf(f0.x, w0, ac[0]); ac[1] = fmaf(f0.y, w0, ac[1]);
        ac[2] = fmaf(f1.x, w0, ac[2]); ac[3] = fmaf(f1.y, w0, ac[3]);
        ac[4] = fmaf(f2.x, w0, ac[4]); ac[5] = fmaf(f2.y, w0, ac[5]);
        ac[6] = fmaf(f3.x, w0, ac[6]); ac[7] = fmaf(f3.y, w0, ac[7]);
    }
    if (gs == 0) {      // self-loop contribution
        float es = asself + adh;
        es = es >= 0.f ? es : NEG * es;
        float w = __expf(es);
        denom += w;
        v2f f0 = __builtin_amdgcn_cvt_pk_f32_fp8((int)rself.x, false);
        v2f f1 = __builtin_amdgcn_cvt_pk_f32_fp8((int)rself.x, true);
        v2f f2 = __builtin_amdgcn_cvt_pk_f32_fp8((int)rself.y, false);
        v2f f3 = __builtin_amdgcn_cvt_pk_f32_fp8((int)rself.y, true);
        ac[0] = fmaf(f0.x, w, ac[0]); ac[1] = fmaf(f0.y, w, ac[1]);
        ac[2] = fmaf(f1.x, w, ac[2]); ac[3] = fmaf(f1.y, w, ac[3]);
        ac[4] = fmaf(f2.x, w, ac[4]); ac[5] = fmaf(f2.y, w, ac[5]);
        ac[6] = fmaf(f3.x, w, ac[6]); ac[7] = fmaf(f3.y, w, ac[7]);
    }
#pragma unroll
    for (int i = 0; i < 8; ++i) {     // reduce 4 slots (stays within 32-half)
        ac[i] += __shfl_xor(ac[i], 8, 64);
        ac[i] += __shfl_xor(ac[i], 16, 64);
    }
    denom += __shfl_xor(denom, 8, 64);
    denom += __shfl_xor(denom, 16, 64);
    if (gs == 0) {
        float inv = 1.0f / denom;
        float4 b0 = ((const float4*)b1)[l * 2];
        float4 b4 = ((const float4*)b1)[l * 2 + 1];
        float4 r0, r1;
        r0.x = fmaf(ac[0], inv, b0.x); r0.x = r0.x > 0.f ? r0.x : expm1f(r0.x);
        r0.y = fmaf(ac[1], inv, b0.y); r0.y = r0.y > 0.f ? r0.y : expm1f(r0.y);
        r0.z = fmaf(ac[2], inv, b0.z); r0.z = r0.z > 0.f ? r0.z : expm1f(r0.z);
        r0.w = fmaf(ac[3], inv, b0.w); r0.w = r0.w > 0.f ? r0.w : expm1f(r0.w);
        r1.x = fmaf(ac[4], inv, b4.x); r1.x = r1.x > 0.f ? r1.x : expm1f(r1.x);
        r1.y = fmaf(ac[5], inv, b4.y); r1.y = r1.y > 0.f ? r1.y : expm1f(r1.y);
        r1.z = fmaf(ac[6], inv, b4.z); r1.z = r1.z > 0.f ? r1.z : expm1f(r1.z);
        r1.w = fmaf(ac[7], inv, b4.w); r1.w = r1.w > 0.f ? r1.w : expm1f(r1.w);
        ((float4*)out)[d * 16 + l * 2]     = r0;
        ((float4*)out)[d * 16 + l * 2 + 1] = r1;
    }
}

// ===========================================================================
// K5: rec = hin @ W2 (fp8 + a_s2 in 128B records) + a_d2. Register-tiled
// 8x8: 256 nodes/block, K=64 in 2 tiles of 32, LDS 48KB. Overwrites the
// layer-1 records (agg1 already complete; stream-ordered).
// ===========================================================================
__global__ __launch_bounds__(256, 3)
void k_lin2(const float* __restrict__ hin, const float* __restrict__ W2,
            const float* __restrict__ att_s, const float* __restrict__ att_d,
            unsigned int* __restrict__ rec, float* __restrict__ a_d) {
    __shared__ float4 sW4[D1 * 16];      // 16 KB
    __shared__ float sxT[32][256];       // 32 KB
    int tid = threadIdx.x;
    const float4* W4 = (const float4*)W2;
    for (int i = tid; i < D1 * 16; i += 256) sW4[i] = W4[i];
    int node0 = blockIdx.x * 256;
    int rg = tid >> 3, cg = tid & 7;
    float acc[8][8];
#pragma unroll
    for (int ii = 0; ii < 8; ++ii)
#pragma unroll
        for (int jj = 0; jj < 8; ++jj) acc[ii][jj] = 0.f;
    const float4* x4 = (const float4*)hin;
    for (int kt = 0; kt < 2; ++kt) {     // K tiles of 32
        if (kt) __syncthreads();
#pragma unroll
        for (int q = 0; q < 8; ++q) {    // stage 256 rows x 32 k, transposed
            int i = q * 256 + tid;
            int r = i >> 3, kc = i & 7;
            int gn = node0 + r;
            float4 v = {0.f, 0.f, 0.f, 0.f};
            if (gn < NN) v = x4[(size_t)gn * 16 + kt * 8 + kc];
            int cs = r ^ (kc << 3);
            sxT[kc * 4 + 0][cs] = v.x;
            sxT[kc * 4 + 1][cs] = v.y;
            sxT[kc * 4 + 2][cs] = v.z;
            sxT[kc * 4 + 3][cs] = v.w;
        }
        __syncthreads();
#pragma unroll 4
        for (int kk = 0; kk < 32; ++kk) {
            int sw = (kk >> 2) << 3;
            const float* xr = &sxT[kk][(rg * 8) ^ sw];
            float4 xa = *(const float4*)xr;
            float4 xb = *(const float4*)(xr + 4);
            int kg = kt * 32 + kk;
            float4 wa = sW4[kg * 16 + cg * 2];
            float4 wb = sW4[kg * 16 + cg * 2 + 1];
            float xv[8] = {xa.x, xa.y, xa.z, xa.w, xb.x, xb.y, xb.z, xb.w};
            float wv[8] = {wa.x, wa.y, wa.z, wa.w, wb.x, wb.y, wb.z, wb.w};
#pragma unroll
            for (int ii = 0; ii < 8; ++ii)
#pragma unroll
                for (int jj = 0; jj < 8; ++jj)
                    acc[ii][jj] = fmaf(xv[ii], wv[jj], acc[ii][jj]);
        }
    }
    // epilogue: fp8 pack + single-head dots (reduce over 8 cg lanes)
    float4 s0 = ((const float4*)att_s)[cg * 2];
    float4 s1 = ((const float4*)att_s)[cg * 2 + 1];
    float4 d0 = ((const float4*)att_d)[cg * 2];
    float4 d1 = ((const float4*)att_d)[cg * 2 + 1];
    uint2* hp2 = (uint2*)rec;
#pragma unroll
    for (int ii = 0; ii < 8; ++ii) {
        int n = node0 + rg * 8 + ii;
        if (n < NN) {
            float* a = acc[ii];
            int p0 = __builtin_amdgcn_cvt_pk_fp8_f32(a[0], a[1], 0, false);
            p0 = __builtin_amdgcn_cvt_pk_fp8_f32(a[2], a[3], p0, true);
            int p1 = __builtin_amdgcn_cvt_pk_fp8_f32(a[4], a[5], 0, false);
            p1 = __builtin_amdgcn_cvt_pk_fp8_f32(a[6], a[7], p1, true);
            uint2 pk; pk.x = (unsigned)p0; pk.y = (unsigned)p1;
            hp2[n * 16 + cg] = pk;
            float vs = a[0] * s0.x;
            vs = fmaf(a[1], s0.y, vs); vs = fmaf(a[2], s0.z, vs);
            vs = fmaf(a[3], s0.w, vs); vs = fmaf(a[4], s1.x, vs);
            vs = fmaf(a[5], s1.y, vs); vs = fmaf(a[6], s1.z, vs);
            vs = fmaf(a[7], s1.w, vs);
            float vd = a[0] * d0.x;
            vd = fmaf(a[1], d0.y, vd); vd = fmaf(a[2], d0.z, vd);
            vd = fmaf(a[3], d0.w, vd); vd = fmaf(a[4], d1.x, vd);
            vd = fmaf(a[5], d1.y, vd); vd = fmaf(a[6], d1.z, vd);
            vd = fmaf(a[7], d1.w, vd);
            vs += __shfl_xor(vs, 1, 64); vs += __shfl_xor(vs, 2, 64);
            vs += __shfl_xor(vs, 4, 64);
            vd += __shfl_xor(vd, 1, 64); vd += __shfl_xor(vd, 2, 64);
            vd += __shfl_xor(vd, 4, 64);
            if (cg == 0) {
                ((float*)rec)[(size_t)n * 32 + 16] = vs;   // byte offset 64
                a_d[n] = vd;
            }
        }
    }
}

// ===========================================================================
// Agg layer 2 (1 head). Same 2-node/wave pipelined structure; a_s2 read
// from the same 128B record line as the h gather. Fused bias + mean-pool.
// ===========================================================================
__global__ __launch_bounds__(256, 8)
void k_gat_agg2(const int* __restrict__ rbeg, const int* __restrict__ rend,
                const int* __restrict__ col,
                const unsigned int* __restrict__ rec, const float* __restrict__ a_d,
                const float* __restrict__ b2, const int* __restrict__ batch,
                float* __restrict__ pool, float* __restrict__ cnt) {
    __shared__ float sv[8][64];
    __shared__ int sgi[8];
    int wv = threadIdx.x >> 6;
    int lane = threadIdx.x & 63;
    int half = lane >> 5;
    int idx = wv * 2 + half;
    int d = blockIdx.x * 8 + idx;
    int gs = (lane >> 3) & 3;
    int l = lane & 7;
    int rb = rbeg[d], re = rend[d];
    float ad = a_d[d];
    const uint2* hp = (const uint2*)rec;
    const float* recf = (const float*)rec;
    uint2 rself = hp[d * 16 + l];
    float asself = recf[d * 32 + 16];
    if (gs == 0 && l == 0) sgi[idx] = batch[d];
    float ac[8] = {0.f,0.f,0.f,0.f,0.f,0.f,0.f,0.f};
    float denom = 0.f;
    int e = rb + gs;
    int s[4];
#pragma unroll
    for (int q = 0; q < 4; ++q) s[q] = col[e + 4 * q];
    for (; e + 12 < re; ) {
        uint2 rr[4]; float asv[4]; int sn[4];
#pragma unroll
        for (int q = 0; q < 4; ++q) rr[q] = hp[(unsigned)(s[q] * 16 + l)];
#pragma unroll
        for (int q = 0; q < 4; ++q) asv[q] = recf[(unsigned)(s[q] * 32 + 16)];
        int en = e + 16;
#pragma unroll
        for (int q = 0; q < 4; ++q) sn[q] = col[en + 4 * q];
#pragma unroll
        for (int q = 0; q < 4; ++q) {
            float xx = asv[q] + ad;
            xx = xx >= 0.f ? xx : NEG * xx;
            float w = __expf(xx);
            denom += w;
            v2f f0 = __builtin_amdgcn_cvt_pk_f32_fp8((int)rr[q].x, false);
            v2f f1 = __builtin_amdgcn_cvt_pk_f32_fp8((int)rr[q].x, true);
            v2f f2 = __builtin_amdgcn_cvt_pk_f32_fp8((int)rr[q].y, false);
            v2f f3 = __builtin_amdgcn_cvt_pk_f32_fp8((int)rr[q].y, true);
            ac[0] = fmaf(f0.x, w, ac[0]); ac[1] = fmaf(f0.y, w, ac[1]);
            ac[2] = fmaf(f1.x, w, ac[2]); ac[3] = fmaf(f1.y, w, ac[3]);
            ac[4] = fmaf(f2.x, w, ac[4]); ac[5] = fmaf(f2.y, w, ac[5]);
            ac[6] = fmaf(f3.x, w, ac[6]); ac[7] = fmaf(f3.y, w, ac[7]);
        }
        e = en;
#pragma unroll
        for (int q = 0; q < 4; ++q) s[q] = sn[q];
    }
    for (; e < re; e += 4) {
        int s0 = col[e];
        uint2 r0 = hp[(unsigned)(s0 * 16 + l)];
        float x0 = recf[(unsigned)(s0 * 32 + 16)] + ad;
        x0 = x0 >= 0.f ? x0 : NEG * x0;
        float w0 = __expf(x0);
        denom += w0;
        v2f f0 = __builtin_amdgcn_cvt_pk_f32_fp8((int)r0.x, false);
        v2f f1 = __builtin_amdgcn_cvt_pk_f32_fp8((int)r0.x, true);
        v2f f2 = __builtin_amdgcn_cvt_pk_f32_fp8((int)r0.y, false);
        v2f f3 = __builtin_amdgcn_cvt_pk_f32_fp8((int)r0.y, true);
        ac[0] = fmaf(f0.x, w0, ac[0]); ac[1] = fmaf(f0.y, w0, ac[1]);
        ac[2] = fmaf(f1.x, w0, ac[2]); ac[3] = fmaf(f1.y, w0, ac[3]);
        ac[4] = fmaf(f2.x, w0, ac[4]); ac[5] = fmaf(f2.y, w0, ac[5]);
        ac[6] = fmaf(f3.x, w0, ac[6]); ac[7] = fmaf(f3.y, w0, ac[7]);
    }
    if (gs == 0) {
        float es = asself + ad;
        es = es >= 0.f ? es : NEG * es;
        float w = __expf(es);
        denom += w;
        v2f f0 = __builtin_amdgcn_cvt_pk_f32_fp8((int)rself.x, false);
        v2f f1 = __builtin_amdgcn_cvt_pk_f32_fp8((int)rself.x, true);
        v2f f2 = __builtin_amdgcn_cvt_pk_f32_fp8((int)rself.y, false);
        v2f f3 = __builtin_amdgcn_cvt_pk_f32_fp8((int)rself.y, true);
        ac[0] = fmaf(f0.x, w, ac[0]); ac[1] = fmaf(f0.y, w, ac[1]);
        ac[2] = fmaf(f1.x, w, ac[2]); ac[3] = fmaf(f1.y, w, ac[3]);
        ac[4] = fmaf(f2.x, w, ac[4]); ac[5] = fmaf(f2.y, w, ac[5]);
        ac[6] = fmaf(f3.x, w, ac[6]); ac[7] = fmaf(f3.y, w, ac[7]);
    }
#pragma unroll
    for (int i = 0; i < 8; ++i) {
        ac[i] += __shfl_xor(ac[i], 8, 64);
        ac[i] += __shfl_xor(ac[i], 16, 64);
    }
    denom += __shfl_xor(denom, 8, 64);
    denom += __shfl_xor(denom, 16, 64);
    if (gs == 0) {
        float inv = 1.0f / denom;
#pragma unroll
        for (int i = 0; i < 8; ++i)
            sv[idx][l * 8 + i] = fmaf(ac[i], inv, b2[l * 8 + i]);
    }
    __syncthreads();
    int tid = threadIdx.x;
    if (tid < 64) {
        float acc = sv[0][tid]; int curg = sgi[0];
        for (int r = 1; r < 8; ++r) {
            if (sgi[r] == curg) acc += sv[r][tid];
            else { atomicAdd(&pool[curg * 64 + tid], acc); curg = sgi[r]; acc = sv[r][tid]; }
        }
        atomicAdd(&pool[curg * 64 + tid], acc);
    } else if (tid == 64) {
        float c = 1.f; int curg = sgi[0];
        for (int r = 1; r < 8; ++r) {
            if (sgi[r] == curg) c += 1.f;
            else { atomicAdd(&cnt[curg], c); curg = sgi[r]; c = 1.f; }
        }
        atomicAdd(&cnt[curg], c);
    }
}

// K9: g = pool/cnt ; hidden = elu(g@lw1+lb1) ; out = hidden@lw2 + lb2
__global__ __launch_bounds__(128)
void k_mlp(const float* __restrict__ pool, const float* __restrict__ cnt,
           const float* __restrict__ lw1, const float* __restrict__ lb1,
           const float* __restrict__ lw2, const float* __restrict__ lb2,
           float* __restrict__ out) {
    __shared__ float sg[OUTC];
    __shared__ float sh[HID];
    int g = blockIdx.x, tid = threadIdx.x;
    float c = fmaxf(cnt[g], 1.0f);
    if (tid < OUTC) sg[tid] = pool[g * OUTC + tid] / c;
    __syncthreads();
    float acc = lb1[tid];
#pragma unroll 8
    for (int k = 0; k < OUTC; ++k)
        acc = fmaf(sg[k], lw1[k * HID + tid], acc);
    acc = acc > 0.f ? acc : expm1f(acc);
    sh[tid] = acc * lw2[tid];
    __syncthreads();
    for (int off = 64; off >= 1; off >>= 1) {
        if (tid < off) sh[tid] += sh[tid + off];
        __syncthreads();
    }
    if (tid == 0) out[g] = sh[0] + lb2[0];
}

extern "C" void kernel_launch(void* const* d_in, const int* in_sizes, int n_in,
                              void* d_out, int out_size, void* d_ws, size_t ws_size,
                              hipStream_t stream) {
    const float* x    = (const float*)d_in[0];
    const int*   ei   = (const int*)d_in[1];
    const int*   batch= (const int*)d_in[2];
    const float* W1   = (const float*)d_in[3];
    const float* as1  = (const float*)d_in[4];
    const float* ad1  = (const float*)d_in[5];
    const float* b1   = (const float*)d_in[6];
    const float* W2   = (const float*)d_in[7];
    const float* as2  = (const float*)d_in[8];
    const float* ad2  = (const float*)d_in[9];
    const float* b2   = (const float*)d_in[10];
    const float* lw1  = (const float*)d_in[11];
    const float* lb1  = (const float*)d_in[12];
    const float* lw2  = (const float*)d_in[13];
    const float* lb2  = (const float*)d_in[14];
    float* out = (float*)d_out;

    // workspace layout (~73 MB); colv has +1024-int pad for pipelined preloads
    unsigned int* REC = (unsigned int*)d_ws;         // N*32 uints = 128B records (12.8 MB)
    float* B    = (float*)(REC + (size_t)NN * 32);   // N*64 fp32 (25.6 MB)
    float* aD1  = B + (size_t)NN * 64;               // N*8
    float* aD2  = aD1 + (size_t)NN * 8;              // N
    float* pool = aD2 + NN;                          // G*64
    float* cntp = pool + GG * 64;                    // G
    int* rbeg   = (int*)(cntp + GG);                 // N
    int* rend   = rbeg + NN;                         // N
    int* cursor = rend + NN;                         // BINS
    int* bucket = cursor + BINS;                     // BINS*BCAP (15.0 MB)
    int* colv   = bucket + (size_t)BINS * BCAP;      // BINS*BCAP + pad

    const int* srcv = ei;
    const int* dstv = ei + EE;

    hipMemsetAsync(cursor, 0, BINS * sizeof(int), stream);
    hipMemsetAsync(pool, 0, (size_t)(GG * 64 + GG) * sizeof(float), stream);

    // FUSED: lin1 GEMM (391 long blocks, first) + bucket scatter (1563 short)
    k_fused<<<NGB + BKBLK, 256, 0, stream>>>(srcv, dstv, cursor, bucket,
                                             x, W1, as1, ad1, REC, aD1);
    k_binCSR<<<BINS, 256, 0, stream>>>(cursor, bucket, colv, rbeg, rend);

    // layer 1 aggregation
    k_gat_agg1<<<NN / 8, 256, 0, stream>>>(rbeg, rend, colv, REC, aD1, b1, B);

    // layer 2 (lin2 overwrites REC with layer-2 records; stream-ordered)
    k_lin2    <<<NGB, 256, 0, stream>>>(B, W2, as2, ad2, REC, aD2);
    k_gat_agg2<<<NN / 8, 256, 0, stream>>>(rbeg, rend, colv, REC, aD2, b2, batch, pool, cntp);

    // MLP head
    k_mlp<<<GG, 128, 0, stream>>>(pool, cntp, lw1, lb1, lw2, lb2, out);
}